// Round 7
// baseline (842.194 us; speedup 1.0000x reference)
//
#include <hip/hip_runtime.h>
#include <hip/hip_bf16.h>

// ---------------------------------------------------------------------------
// CFGSubASTExpressionCombiner: counting-sort by segment, then BARRIER-FREE
// direct-fragment MFMA GEMMs (no LDS): each lane loads its 16B A/B fragment
// straight from global (A = gathered fp32 row -> cvt_pk_bf16; B = bf16
// weights, L2-resident). Fused K|V (one gather), CSR softmax+pool, out GEMM.
// D = 256, H = 8, HD = 32, OUT = 256.
// NOTES:
//  - no hipMemsetAsync in the graph (in-graph small fills ~235us each, r3).
//  - scan is 3-phase multi-block (single-block scan was 233us on 1 CU, r4).
//  - r6 LDS-staged fused GEMM was latency-bound (occ 22%, HBM 7%, 16 barriers
//    per block, 1.3e7 bank-conflict cycles) -> this rewrite removes LDS and
//    barriers entirely; MFMA A-fragments are 16B/lane contiguous so gathers
//    feed MFMA directly.
// ---------------------------------------------------------------------------

typedef __attribute__((ext_vector_type(8))) short bf16x8;
typedef __attribute__((ext_vector_type(4))) float f32x4;

#define DEV __device__ __forceinline__

DEV float bf2f(unsigned short u) {
    union { unsigned int i; float f; } x;
    x.i = ((unsigned int)u) << 16;
    return x.f;
}

DEV unsigned short f2bf(float f) {
    union { float f; unsigned int i; } x;
    x.f = f;
    unsigned int i = x.i;
    unsigned int r = 0x7fffu + ((i >> 16) & 1u);   // round-to-nearest-even
    return (unsigned short)((i + r) >> 16);
}

// 8 consecutive fp32 -> bf16x8 via v_cvt_pk_bf16_f32 (4 instrs)
DEV bf16x8 cvt8(float4 lo, float4 hi) {
    union { bf16x8 v; unsigned int u[4]; } r;
    asm("v_cvt_pk_bf16_f32 %0, %1, %2" : "=v"(r.u[0]) : "v"(lo.x), "v"(lo.y));
    asm("v_cvt_pk_bf16_f32 %0, %1, %2" : "=v"(r.u[1]) : "v"(lo.z), "v"(lo.w));
    asm("v_cvt_pk_bf16_f32 %0, %1, %2" : "=v"(r.u[2]) : "v"(hi.x), "v"(hi.y));
    asm("v_cvt_pk_bf16_f32 %0, %1, %2" : "=v"(r.u[3]) : "v"(hi.z), "v"(hi.w));
    return r.v;
}

// ---------------------------------------------------------------------------
// Weight prep: transpose fp32 [K][N] weights into bf16 [N][K] layout.
// ---------------------------------------------------------------------------
__global__ void convert_weights(const float* __restrict__ Wq,
                                const float* __restrict__ Wk,
                                const float* __restrict__ Wv,
                                const float* __restrict__ Wo,
                                unsigned short* __restrict__ Wtq,
                                unsigned short* __restrict__ Wtk,
                                unsigned short* __restrict__ Wtv,
                                unsigned short* __restrict__ Wto) {
    int t = blockIdx.x * 256 + threadIdx.x;
    if (t >= 4 * 65536) return;
    int which = t >> 16;
    int u = t & 65535;
    int n = u >> 8, k = u & 255;
    const float* W = which == 0 ? Wq : which == 1 ? Wk : which == 2 ? Wv : Wo;
    unsigned short* Wt = which == 0 ? Wtq : which == 1 ? Wtk : which == 2 ? Wtv : Wto;
    Wt[u] = f2bf(W[k * 256 + n]);
}

// ---------------------------------------------------------------------------
// Counting sort of mapping entries by segment id.
// ---------------------------------------------------------------------------
__global__ void zero_kernel(int* __restrict__ p, int n) {
    int i = blockIdx.x * 256 + threadIdx.x;
    if (i < n) p[i] = 0;
}

__global__ void hist_kernel(const int* __restrict__ map_val,
                            int* __restrict__ counts, int M) {
    int m = blockIdx.x * 256 + threadIdx.x;
    if (m < M) atomicAdd(&counts[map_val[m]], 1);
}

// ---- 3-phase exclusive scan over counts[S] -> offsets[S+1], cursor[S] ----
__global__ __launch_bounds__(256) void scan_p1(const int* __restrict__ counts,
                                               int* __restrict__ bsum, int S) {
    const int i = blockIdx.x * 256 + threadIdx.x;
    int v = (i < S) ? counts[i] : 0;
#pragma unroll
    for (int d = 1; d < 64; d <<= 1) v += __shfl_xor(v, d);
    __shared__ int ws[4];
    if ((threadIdx.x & 63) == 0) ws[threadIdx.x >> 6] = v;
    __syncthreads();
    if (threadIdx.x == 0) bsum[blockIdx.x] = ws[0] + ws[1] + ws[2] + ws[3];
}

__global__ __launch_bounds__(256) void scan_p2(const int* __restrict__ bsum,
                                               int* __restrict__ bpref,
                                               int* __restrict__ offsets,
                                               int nb, int S) {
    __shared__ int part[256];
    const int t = threadIdx.x;
    const int chunk = (nb + 255) / 256;
    const int lo = t * chunk;
    const int hi = min(lo + chunk, nb);
    int sum = 0;
    for (int i = lo; i < hi; ++i) sum += bsum[i];
    part[t] = sum;
    __syncthreads();
    for (int d = 1; d < 256; d <<= 1) {
        int v = (t >= d) ? part[t - d] : 0;
        __syncthreads();
        part[t] += v;
        __syncthreads();
    }
    int run = (t > 0) ? part[t - 1] : 0;
    for (int i = lo; i < hi; ++i) {
        bpref[i] = run;
        run += bsum[i];
    }
    if (t == 255) offsets[S] = part[255];
}

__global__ __launch_bounds__(256) void scan_p3(const int* __restrict__ counts,
                                               const int* __restrict__ bpref,
                                               int* __restrict__ offsets,
                                               int* __restrict__ cursor, int S) {
    __shared__ int sh[256];
    const int t = threadIdx.x;
    const int i = blockIdx.x * 256 + t;
    const int v = (i < S) ? counts[i] : 0;
    sh[t] = v;
    __syncthreads();
    for (int d = 1; d < 256; d <<= 1) {
        int u = (t >= d) ? sh[t - d] : 0;
        __syncthreads();
        sh[t] += u;
        __syncthreads();
    }
    if (i < S) {
        const int e = sh[t] - v + bpref[blockIdx.x];
        offsets[i] = e;
        cursor[i] = e;
    }
}

__global__ void scatter_kernel(const int* __restrict__ map_key,
                               const int* __restrict__ map_val,
                               int* __restrict__ cursor,
                               int* __restrict__ sorted_src, int M) {
    int m = blockIdx.x * 256 + threadIdx.x;
    if (m >= M) return;
    int seg = map_val[m];
    int pos = atomicAdd(&cursor[seg], 1);
    sorted_src[pos] = map_key[m];
}

// ---------------------------------------------------------------------------
// Direct-fragment GEMM (no LDS, no barriers).
// Block = 256 threads = 4 waves; block owns 64 rows; wave w owns cols w*64..+63.
// Per k-slice (32): lane loads A-frag = A[src(row)][koct*8..+8] (16B) and
// B-frag = Wt[col][same 16B]; 16 MFMA per k-slice (32 if FUSE: K and V).
// A fp32 rows are converted in-register via v_cvt_pk_bf16_f32.
// ---------------------------------------------------------------------------
template <bool GATHER, bool SCATTER, bool A_F32, bool OUT_F32, bool FUSE, int MINW>
__global__ __launch_bounds__(256, MINW) void gemm_direct(
    const void* __restrict__ Aptr,
    const int* __restrict__ srcIdx,
    const int* __restrict__ dstIdx,
    const unsigned short* __restrict__ Wt0,
    const unsigned short* __restrict__ Wt1,
    const float* __restrict__ bias0,
    const float* __restrict__ bias1,
    void* __restrict__ Out,
    int nrows, int ldo) {
    const int tid = threadIdx.x;
    const int wave = tid >> 6, lane = tid & 63;
    const int lrow = lane & 15;          // row (A) / col (B) within 16
    const int koct = (lane >> 4) * 8;    // k-octet within the 32-k slice
    const long rbase = (long)blockIdx.x * 64;
    const int colb = wave * 64;

    // per-lane source rows for the 4 row-blocks (shared across waves -> L1)
    int src[4];
#pragma unroll
    for (int i = 0; i < 4; ++i) {
        long gr = rbase + i * 16 + lrow;
        if (gr >= nrows) gr = nrows - 1;   // safe read; stores masked below
        src[i] = GATHER ? srcIdx[gr] : (int)gr;
    }

    f32x4 acc0[4][4] = {};
    f32x4 acc1[4][4] = {};

#pragma unroll
    for (int kt = 0; kt < 8; ++kt) {
        const int k0 = kt * 32 + koct;
        bf16x8 a[4];
        if constexpr (A_F32) {
#pragma unroll
            for (int i = 0; i < 4; ++i) {
                const float* p = (const float*)Aptr + (long)src[i] * 256 + k0;
                const float4 lo = *(const float4*)p;
                const float4 hi = *(const float4*)(p + 4);
                a[i] = cvt8(lo, hi);
            }
        } else {
#pragma unroll
            for (int i = 0; i < 4; ++i)
                a[i] = *(const bf16x8*)((const unsigned short*)Aptr + (long)src[i] * 256 + k0);
        }

        bf16x8 b[4];
#pragma unroll
        for (int j = 0; j < 4; ++j)
            b[j] = *(const bf16x8*)(Wt0 + (long)(colb + j * 16 + lrow) * 256 + k0);
#pragma unroll
        for (int i = 0; i < 4; ++i)
#pragma unroll
            for (int j = 0; j < 4; ++j)
                acc0[i][j] = __builtin_amdgcn_mfma_f32_16x16x32_bf16(a[i], b[j], acc0[i][j], 0, 0, 0);

        if constexpr (FUSE) {
            bf16x8 c[4];
#pragma unroll
            for (int j = 0; j < 4; ++j)
                c[j] = *(const bf16x8*)(Wt1 + (long)(colb + j * 16 + lrow) * 256 + k0);
#pragma unroll
            for (int i = 0; i < 4; ++i)
#pragma unroll
                for (int j = 0; j < 4; ++j)
                    acc1[i][j] = __builtin_amdgcn_mfma_f32_16x16x32_bf16(a[i], c[j], acc1[i][j], 0, 0, 0);
        }
    }

    // ---- epilogue: C/D layout col=lane&15, row=(lane>>4)*4+rj ----
#pragma unroll
    for (int i = 0; i < 4; ++i) {
#pragma unroll
        for (int j = 0; j < 4; ++j) {
            const int col = colb + j * 16 + lrow;
            const float bs0 = bias0[col];
            const float bs1 = FUSE ? bias1[col] : 0.0f;
#pragma unroll
            for (int rj = 0; rj < 4; ++rj) {
                const long row = rbase + i * 16 + (lane >> 4) * 4 + rj;
                if (row < nrows) {
                    const long drow = SCATTER ? (long)dstIdx[row] : row;
                    if constexpr (FUSE) {
                        unsigned short* o = (unsigned short*)Out + drow * 512;
                        o[col]       = f2bf(acc0[i][j][rj] + bs0);
                        o[col + 256] = f2bf(acc1[i][j][rj] + bs1);
                    } else if constexpr (OUT_F32) {
                        ((float*)Out)[drow * ldo + col] = acc0[i][j][rj] + bs0;
                    } else {
                        ((unsigned short*)Out)[drow * ldo + col] = f2bf(acc0[i][j][rj] + bs0);
                    }
                }
            }
        }
    }
}

// ---------------------------------------------------------------------------
// CSR pooling: one wave per segment s; kv rows for s are [offsets[s],offsets[s+1]).
// score_h = <k[e,h,:], q[s,h,:]>*scale ; ew = exp(score) (shift-free; |score|<~1)
// pooled[s] = sum ew*v / sum ew, written bf16 IN PLACE over q[s].
// ---------------------------------------------------------------------------
__global__ __launch_bounds__(256) void pool_csr_kernel(
    unsigned short* __restrict__ q,          // bf16 [S][256] (in: q, out: pooled)
    const unsigned short* __restrict__ kv,   // bf16 [Msorted][512] (k | v)
    const int* __restrict__ offsets,         // [S+1]
    int S) {
    const int s = blockIdx.x * 4 + (threadIdx.x >> 6);
    if (s >= S) return;
    const int lane = threadIdx.x & 63;
    const int beg = offsets[s];
    const int end = offsets[s + 1];

    const ushort4 qv = *(const ushort4*)(q + (long)s * 256 + lane * 4);
    const float q0 = bf2f(qv.x), q1 = bf2f(qv.y), q2 = bf2f(qv.z), q3 = bf2f(qv.w);

    float a0 = 0.f, a1 = 0.f, a2 = 0.f, a3 = 0.f, denom = 0.f;

    for (int e = beg; e < end; ++e) {
        const ushort4 kk = *(const ushort4*)(kv + (long)e * 512 + lane * 4);
        const ushort4 vv = *(const ushort4*)(kv + (long)e * 512 + 256 + lane * 4);
        float p = q0 * bf2f(kk.x) + q1 * bf2f(kk.y) + q2 * bf2f(kk.z) + q3 * bf2f(kk.w);
        p += __shfl_xor(p, 1);
        p += __shfl_xor(p, 2);
        p += __shfl_xor(p, 4);   // 8-lane head group holds the head dot
        const float ew = expf(p * 0.17677669529663687f);  // 1/sqrt(32)
        a0 += ew * bf2f(vv.x);
        a1 += ew * bf2f(vv.y);
        a2 += ew * bf2f(vv.z);
        a3 += ew * bf2f(vv.w);
        denom += ew;
    }

    const float w = 1.0f / fmaxf(denom, 1e-9f);
    ushort4 o;
    o.x = f2bf(a0 * w);
    o.y = f2bf(a1 * w);
    o.z = f2bf(a2 * w);
    o.w = f2bf(a3 * w);
    *(ushort4*)(q + (long)s * 256 + lane * 4) = o;
}

// ---------------------------------------------------------------------------
extern "C" void kernel_launch(void* const* d_in, const int* in_sizes, int n_in,
                              void* d_out, int out_size, void* d_ws, size_t ws_size,
                              hipStream_t stream) {
    const float* enc  = (const float*)d_in[0];
    const float* W_q  = (const float*)d_in[1];
    const float* b_q  = (const float*)d_in[2];
    const float* W_k  = (const float*)d_in[3];
    const float* b_k  = (const float*)d_in[4];
    const float* W_v  = (const float*)d_in[5];
    const float* b_v  = (const float*)d_in[6];
    const float* W_o  = (const float*)d_in[7];
    const float* b_o  = (const float*)d_in[8];
    const int* map_key = (const int*)d_in[9];    // [M] ast idx
    const int* map_val = (const int*)d_in[10];   // [M] cfg idx (segment id)
    const int* pdg_key = (const int*)d_in[11];   // [S] dst rows (bijection)
    const int* pdg_val = (const int*)d_in[12];   // [S] src ast rows

    const int M = in_sizes[9];
    const int S = in_sizes[11];
    const int NB = (S + 255) / 256;

    char* ws = (char*)d_ws;
    size_t off = 0;
    auto alloc = [&](size_t bytes) -> char* {
        char* p = ws + off;
        off += (bytes + 255) & ~(size_t)255;
        return p;
    };

    unsigned short* Wt_q  = (unsigned short*)alloc(256 * 256 * 2);
    unsigned short* Wt_k  = (unsigned short*)alloc(256 * 256 * 2);
    unsigned short* Wt_v  = (unsigned short*)alloc(256 * 256 * 2);
    unsigned short* Wt_o  = (unsigned short*)alloc(256 * 256 * 2);
    int*            counts  = (int*)alloc((size_t)S * 4);
    int*            cursor  = (int*)alloc((size_t)S * 4);
    int*            offsets = (int*)alloc((size_t)(S + 1) * 4);
    int*            bsum    = (int*)alloc((size_t)NB * 4);
    int*            bpref   = (int*)alloc((size_t)NB * 4);
    int*            sorted_src = (int*)alloc((size_t)M * 4);
    unsigned short* qbuf  = (unsigned short*)alloc((size_t)S * 256 * 2);  // q, then pooled
    unsigned short* kvbuf = (unsigned short*)alloc((size_t)M * 512 * 2);

    // zero counts with a plain kernel (NOT hipMemsetAsync)
    zero_kernel<<<(S + 255) / 256, 256, 0, stream>>>(counts, S);

    convert_weights<<<1024, 256, 0, stream>>>(W_q, W_k, W_v, W_o, Wt_q, Wt_k, Wt_v, Wt_o);

    // counting sort of mapping entries by segment
    hist_kernel<<<(M + 255) / 256, 256, 0, stream>>>(map_val, counts, M);
    scan_p1<<<NB, 256, 0, stream>>>(counts, bsum, S);
    scan_p2<<<1, 256, 0, stream>>>(bsum, bpref, offsets, NB, S);
    scan_p3<<<NB, 256, 0, stream>>>(counts, bpref, offsets, cursor, S);
    scatter_kernel<<<(M + 255) / 256, 256, 0, stream>>>(
        map_key, map_val, cursor, sorted_src, M);

    // Q projection: q[pdg_key[i]] = enc[pdg_val[i]] @ W_q + b_q  (fp32 gather)
    gemm_direct<true, true, true, false, false, 4><<<(S + 63) / 64, 256, 0, stream>>>(
        enc, pdg_val, pdg_key, Wt_q, nullptr, b_q, nullptr, qbuf, S, 256);

    // fused K|V projection: kv[i] = enc[sorted_src[i]] @ [W_k|W_v] + [b_k|b_v]
    gemm_direct<true, false, true, false, true, 2><<<(M + 63) / 64, 256, 0, stream>>>(
        enc, sorted_src, nullptr, Wt_k, Wt_v, b_k, b_v, kvbuf, M, 512);

    // CSR segment softmax + pooling; pooled overwrites qbuf
    pool_csr_kernel<<<(S + 3) / 4, 256, 0, stream>>>(qbuf, kvbuf, offsets, S);

    // output projection to d_out (fp32)
    gemm_direct<false, false, false, true, false, 4><<<(S + 63) / 64, 256, 0, stream>>>(
        qbuf, nullptr, nullptr, Wt_o, nullptr, b_o, nullptr, d_out, S, 256);
}

// Round 8
// 707.007 us; speedup vs baseline: 1.1912x; 1.1912x over previous
//
#include <hip/hip_runtime.h>
#include <hip/hip_bf16.h>

// ---------------------------------------------------------------------------
// CFGSubASTExpressionCombiner.
// Structure (r8): project K|V for ALL N_AST rows (M == N_AST, so same FLOPs)
// with a STREAMING GEMM (no gather) -> pool gathers kv_all[ast_idx] rows.
// Q proj gathers 100k fp32 rows; out proj streams. All GEMMs: 64-row tile,
// single barrier, A staged fp32->bf16 in LDS, B direct from L2 weights.
// D = 256, H = 8, HD = 32, OUT = 256.
// NOTES:
//  - no hipMemsetAsync in the graph (in-graph small fills ~235us each, r3).
//  - scan is 3-phase multi-block (single-block scan was 233us on 1 CU, r4).
//  - r6 LDS 4-barrier/ktile GEMM: latency-bound (occ 22%, HBM 7%).
//  - r7 no-LDS direct-fragment GEMM: worse (gather latency in MFMA pipe,
//    4x redundant row loads across waves). Gather removed from GEMM instead.
// ---------------------------------------------------------------------------

typedef __attribute__((ext_vector_type(8))) short bf16x8;
typedef __attribute__((ext_vector_type(4))) float f32x4;

#define DEV __device__ __forceinline__

DEV float bf2f(unsigned short u) {
    union { unsigned int i; float f; } x;
    x.i = ((unsigned int)u) << 16;
    return x.f;
}

DEV unsigned short f2bf(float f) {
    union { float f; unsigned int i; } x;
    x.f = f;
    unsigned int i = x.i;
    unsigned int r = 0x7fffu + ((i >> 16) & 1u);   // round-to-nearest-even
    return (unsigned short)((i + r) >> 16);
}

// 8 consecutive fp32 -> bf16x8 via v_cvt_pk_bf16_f32 (4 instrs)
DEV bf16x8 cvt8(float4 lo, float4 hi) {
    union { bf16x8 v; unsigned int u[4]; } r;
    asm("v_cvt_pk_bf16_f32 %0, %1, %2" : "=v"(r.u[0]) : "v"(lo.x), "v"(lo.y));
    asm("v_cvt_pk_bf16_f32 %0, %1, %2" : "=v"(r.u[1]) : "v"(lo.z), "v"(lo.w));
    asm("v_cvt_pk_bf16_f32 %0, %1, %2" : "=v"(r.u[2]) : "v"(hi.x), "v"(hi.y));
    asm("v_cvt_pk_bf16_f32 %0, %1, %2" : "=v"(r.u[3]) : "v"(hi.z), "v"(hi.w));
    return r.v;
}

// ---------------------------------------------------------------------------
// Weight prep: Wt_q[256][256], Wt_kv[512][256] (K cols then V cols),
// Wt_o[256][256] in bf16 [N][K] layout; b_kv = bK|bV.
// ---------------------------------------------------------------------------
__global__ void convert_weights(const float* __restrict__ Wq,
                                const float* __restrict__ Wk,
                                const float* __restrict__ Wv,
                                const float* __restrict__ Wo,
                                const float* __restrict__ bk,
                                const float* __restrict__ bv,
                                unsigned short* __restrict__ Wtq,
                                unsigned short* __restrict__ Wtkv,
                                unsigned short* __restrict__ Wto,
                                float* __restrict__ bkv) {
    int t = blockIdx.x * 256 + threadIdx.x;
    if (t < 65536) {
        int n = t >> 8, k = t & 255;
        Wtq[t] = f2bf(Wq[k * 256 + n]);
    } else if (t < 65536 + 131072) {
        int u = t - 65536;
        int n = u >> 8, k = u & 255;
        Wtkv[u] = f2bf(n < 256 ? Wk[k * 256 + n] : Wv[k * 256 + (n - 256)]);
    } else if (t < 196608 + 65536) {
        int u = t - 196608;
        int n = u >> 8, k = u & 255;
        Wto[u] = f2bf(Wo[k * 256 + n]);
    } else if (t < 262144 + 512) {
        int c = t - 262144;
        bkv[c] = c < 256 ? bk[c] : bv[c - 256];
    }
}

// ---------------------------------------------------------------------------
// Counting sort of mapping entries by segment id.
// ---------------------------------------------------------------------------
__global__ void zero_kernel(int* __restrict__ p, int n) {
    int i = blockIdx.x * 256 + threadIdx.x;
    if (i < n) p[i] = 0;
}

__global__ void hist_kernel(const int* __restrict__ map_val,
                            int* __restrict__ counts, int M) {
    int m = blockIdx.x * 256 + threadIdx.x;
    if (m < M) atomicAdd(&counts[map_val[m]], 1);
}

// ---- 3-phase exclusive scan over counts[S] -> offsets[S+1], cursor[S] ----
__global__ __launch_bounds__(256) void scan_p1(const int* __restrict__ counts,
                                               int* __restrict__ bsum, int S) {
    const int i = blockIdx.x * 256 + threadIdx.x;
    int v = (i < S) ? counts[i] : 0;
#pragma unroll
    for (int d = 1; d < 64; d <<= 1) v += __shfl_xor(v, d);
    __shared__ int ws[4];
    if ((threadIdx.x & 63) == 0) ws[threadIdx.x >> 6] = v;
    __syncthreads();
    if (threadIdx.x == 0) bsum[blockIdx.x] = ws[0] + ws[1] + ws[2] + ws[3];
}

__global__ __launch_bounds__(256) void scan_p2(const int* __restrict__ bsum,
                                               int* __restrict__ bpref,
                                               int* __restrict__ offsets,
                                               int nb, int S) {
    __shared__ int part[256];
    const int t = threadIdx.x;
    const int chunk = (nb + 255) / 256;
    const int lo = t * chunk;
    const int hi = min(lo + chunk, nb);
    int sum = 0;
    for (int i = lo; i < hi; ++i) sum += bsum[i];
    part[t] = sum;
    __syncthreads();
    for (int d = 1; d < 256; d <<= 1) {
        int v = (t >= d) ? part[t - d] : 0;
        __syncthreads();
        part[t] += v;
        __syncthreads();
    }
    int run = (t > 0) ? part[t - 1] : 0;
    for (int i = lo; i < hi; ++i) {
        bpref[i] = run;
        run += bsum[i];
    }
    if (t == 255) offsets[S] = part[255];
}

__global__ __launch_bounds__(256) void scan_p3(const int* __restrict__ counts,
                                               const int* __restrict__ bpref,
                                               int* __restrict__ offsets,
                                               int* __restrict__ cursor, int S) {
    __shared__ int sh[256];
    const int t = threadIdx.x;
    const int i = blockIdx.x * 256 + t;
    const int v = (i < S) ? counts[i] : 0;
    sh[t] = v;
    __syncthreads();
    for (int d = 1; d < 256; d <<= 1) {
        int u = (t >= d) ? sh[t - d] : 0;
        __syncthreads();
        sh[t] += u;
        __syncthreads();
    }
    if (i < S) {
        const int e = sh[t] - v + bpref[blockIdx.x];
        offsets[i] = e;
        cursor[i] = e;
    }
}

__global__ void scatter_kernel(const int* __restrict__ map_key,
                               const int* __restrict__ map_val,
                               int* __restrict__ cursor,
                               int* __restrict__ sorted_src, int M) {
    int m = blockIdx.x * 256 + threadIdx.x;
    if (m >= M) return;
    int seg = map_val[m];
    int pos = atomicAdd(&cursor[seg], 1);
    sorted_src[pos] = map_key[m];   // ast row of this sorted entry
}

// ---------------------------------------------------------------------------
// 64-row single-barrier GEMM.  Out[dst(r)][n] = sum_k A[src(r)][k]*Wt[n][k]+bias[n]
// Block = NW*64 threads (NW waves); block owns 64 rows, wave w owns cols
// w*64..+63 of the NW*64-wide output. A (fp32 or bf16) staged ONCE into LDS
// (fp32 converted via cvt_pk_bf16); B fragments read directly from L2-resident
// bf16 weights. One __syncthreads per block. LDS rows padded to 264 (2-way max).
// ---------------------------------------------------------------------------
template <bool GATHER, bool SCATTER, bool A_F32, bool OUT_F32, int NW, int MINB>
__global__ __launch_bounds__(NW * 64, MINB) void gemm64(
    const void* __restrict__ Aptr,
    const int* __restrict__ srcIdx,
    const int* __restrict__ dstIdx,
    const unsigned short* __restrict__ Wt,   // bf16 [NW*64][256]
    const float* __restrict__ bias,          // [NW*64]
    void* __restrict__ Out,
    int nrows, int ldo) {
    __shared__ unsigned short Alds[64][264];

    constexpr int NT = NW * 64;
    constexpr int F = 16384 / NT;   // fp32/bf16 elems staged per thread

    const int tid = threadIdx.x;
    const long rbase = (long)blockIdx.x * 64;

    // ---- stage A tile (64 rows x 256) ----
    {
        const int l0 = tid * F;
        const int row = l0 >> 8;
        const int col0 = l0 & 255;
        long gr = rbase + row;
        if (gr > nrows - 1) gr = nrows - 1;         // safe row; stores masked
        const long src = GATHER ? (long)srcIdx[gr] : gr;
        if constexpr (A_F32) {
            const float* ap = (const float*)Aptr + src * 256 + col0;
#pragma unroll
            for (int u = 0; u < F; u += 8) {
                const float4 lo = *(const float4*)(ap + u);
                const float4 hi = *(const float4*)(ap + u + 4);
                *(bf16x8*)(&Alds[row][col0 + u]) = cvt8(lo, hi);
            }
        } else {
            const unsigned short* ap = (const unsigned short*)Aptr + src * 256 + col0;
#pragma unroll
            for (int u = 0; u < F; u += 8)
                *(bf16x8*)(&Alds[row][col0 + u]) = *(const bf16x8*)(ap + u);
        }
    }
    __syncthreads();

    // ---- compute ----
    const int wave = tid >> 6, lane = tid & 63;
    const int lrow = lane & 15;
    const int koct = (lane >> 4) * 8;
    const int colb = wave * 64;

    f32x4 acc[4][4] = {};

#pragma unroll
    for (int kt = 0; kt < 8; ++kt) {
        const int k0 = kt * 32 + koct;
        bf16x8 a[4], b[4];
#pragma unroll
        for (int i = 0; i < 4; ++i)
            a[i] = *(const bf16x8*)(&Alds[i * 16 + lrow][k0]);
#pragma unroll
        for (int j = 0; j < 4; ++j)
            b[j] = *(const bf16x8*)(Wt + (long)(colb + j * 16 + lrow) * 256 + k0);
#pragma unroll
        for (int i = 0; i < 4; ++i)
#pragma unroll
            for (int j = 0; j < 4; ++j)
                acc[i][j] = __builtin_amdgcn_mfma_f32_16x16x32_bf16(a[i], b[j], acc[i][j], 0, 0, 0);
    }

    // ---- epilogue: C/D col=lane&15, row=(lane>>4)*4+rj ----
#pragma unroll
    for (int i = 0; i < 4; ++i) {
#pragma unroll
        for (int j = 0; j < 4; ++j) {
            const int col = colb + j * 16 + lrow;
            const float bs = bias[col];
#pragma unroll
            for (int rj = 0; rj < 4; ++rj) {
                const long row = rbase + i * 16 + (lane >> 4) * 4 + rj;
                if (row < nrows) {
                    const long drow = SCATTER ? (long)dstIdx[row] : row;
                    const float val = acc[i][j][rj] + bs;
                    if constexpr (OUT_F32)
                        ((float*)Out)[drow * ldo + col] = val;
                    else
                        ((unsigned short*)Out)[drow * ldo + col] = f2bf(val);
                }
            }
        }
    }
}

// ---------------------------------------------------------------------------
// CSR pooling: one wave per segment s; entries e in [offsets[s],offsets[s+1]),
// each entry's K/V row is kv_all[sorted_src[e]] (gathered).
// score_h = <k,q_h>*scale; ew = exp(score) (shift-free; |score|<~1)
// pooled[s] = sum ew*v / sum ew, written bf16 IN PLACE over q[s].
// ---------------------------------------------------------------------------
__global__ __launch_bounds__(256) void pool_csr_kernel(
    unsigned short* __restrict__ q,          // bf16 [S][256] (in: q, out: pooled)
    const unsigned short* __restrict__ kv,   // bf16 [N_AST][512] (k | v)
    const int* __restrict__ offsets,         // [S+1]
    const int* __restrict__ sorted_src,      // [M] ast row per sorted entry
    int S) {
    const int s = blockIdx.x * 4 + (threadIdx.x >> 6);
    if (s >= S) return;
    const int lane = threadIdx.x & 63;
    const int beg = offsets[s];
    const int end = offsets[s + 1];

    const ushort4 qv = *(const ushort4*)(q + (long)s * 256 + lane * 4);
    const float q0 = bf2f(qv.x), q1 = bf2f(qv.y), q2 = bf2f(qv.z), q3 = bf2f(qv.w);

    float a0 = 0.f, a1 = 0.f, a2 = 0.f, a3 = 0.f, denom = 0.f;

    for (int e = beg; e < end; ++e) {
        const long mrow = sorted_src[e];
        const ushort4 kk = *(const ushort4*)(kv + mrow * 512 + lane * 4);
        const ushort4 vv = *(const ushort4*)(kv + mrow * 512 + 256 + lane * 4);
        float p = q0 * bf2f(kk.x) + q1 * bf2f(kk.y) + q2 * bf2f(kk.z) + q3 * bf2f(kk.w);
        p += __shfl_xor(p, 1);
        p += __shfl_xor(p, 2);
        p += __shfl_xor(p, 4);   // 8-lane head group holds the head dot
        const float ew = expf(p * 0.17677669529663687f);  // 1/sqrt(32)
        a0 += ew * bf2f(vv.x);
        a1 += ew * bf2f(vv.y);
        a2 += ew * bf2f(vv.z);
        a3 += ew * bf2f(vv.w);
        denom += ew;
    }

    const float w = 1.0f / fmaxf(denom, 1e-9f);
    ushort4 o;
    o.x = f2bf(a0 * w);
    o.y = f2bf(a1 * w);
    o.z = f2bf(a2 * w);
    o.w = f2bf(a3 * w);
    *(ushort4*)(q + (long)s * 256 + lane * 4) = o;
}

// ---------------------------------------------------------------------------
extern "C" void kernel_launch(void* const* d_in, const int* in_sizes, int n_in,
                              void* d_out, int out_size, void* d_ws, size_t ws_size,
                              hipStream_t stream) {
    const float* enc  = (const float*)d_in[0];
    const float* W_q  = (const float*)d_in[1];
    const float* b_q  = (const float*)d_in[2];
    const float* W_k  = (const float*)d_in[3];
    const float* b_k  = (const float*)d_in[4];
    const float* W_v  = (const float*)d_in[5];
    const float* b_v  = (const float*)d_in[6];
    const float* W_o  = (const float*)d_in[7];
    const float* b_o  = (const float*)d_in[8];
    const int* map_key = (const int*)d_in[9];    // [M] ast idx
    const int* map_val = (const int*)d_in[10];   // [M] cfg idx (segment id)
    const int* pdg_key = (const int*)d_in[11];   // [S] dst rows (bijection)
    const int* pdg_val = (const int*)d_in[12];   // [S] src ast rows

    const int M = in_sizes[9];
    const int S = in_sizes[11];
    const int NAST = in_sizes[0] / 256;
    const int NB = (S + 255) / 256;

    char* ws = (char*)d_ws;
    size_t off = 0;
    auto alloc = [&](size_t bytes) -> char* {
        char* p = ws + off;
        off += (bytes + 255) & ~(size_t)255;
        return p;
    };

    unsigned short* Wt_q  = (unsigned short*)alloc(256 * 256 * 2);
    unsigned short* Wt_kv = (unsigned short*)alloc(512 * 256 * 2);
    unsigned short* Wt_o  = (unsigned short*)alloc(256 * 256 * 2);
    float*          b_kv  = (float*)alloc(512 * 4);
    int*            counts  = (int*)alloc((size_t)S * 4);
    int*            cursor  = (int*)alloc((size_t)S * 4);
    int*            offsets = (int*)alloc((size_t)(S + 1) * 4);
    int*            bsum    = (int*)alloc((size_t)NB * 4);
    int*            bpref   = (int*)alloc((size_t)NB * 4);
    int*            sorted_src = (int*)alloc((size_t)M * 4);
    unsigned short* qbuf   = (unsigned short*)alloc((size_t)S * 256 * 2);   // q, then pooled
    unsigned short* kv_all = (unsigned short*)alloc((size_t)NAST * 512 * 2);

    // zero counts with a plain kernel (NOT hipMemsetAsync)
    zero_kernel<<<(S + 255) / 256, 256, 0, stream>>>(counts, S);

    convert_weights<<<(262656 + 255) / 256, 256, 0, stream>>>(
        W_q, W_k, W_v, W_o, b_k, b_v, Wt_q, Wt_kv, Wt_o, b_kv);

    // counting sort of mapping entries by segment (gives CSR entry->ast row)
    hist_kernel<<<(M + 255) / 256, 256, 0, stream>>>(map_val, counts, M);
    scan_p1<<<NB, 256, 0, stream>>>(counts, bsum, S);
    scan_p2<<<1, 256, 0, stream>>>(bsum, bpref, offsets, NB, S);
    scan_p3<<<NB, 256, 0, stream>>>(counts, bpref, offsets, cursor, S);
    scatter_kernel<<<(M + 255) / 256, 256, 0, stream>>>(
        map_key, map_val, cursor, sorted_src, M);

    // K|V projection for ALL ast rows (streaming, no gather):
    // kv_all[r][0:512] = enc[r] @ [W_k | W_v] + [b_k | b_v]
    gemm64<false, false, true, false, 8, 2><<<(NAST + 63) / 64, 512, 0, stream>>>(
        enc, nullptr, nullptr, Wt_kv, b_kv, kv_all, NAST, 512);

    // Q projection: q[pdg_key[i]] = enc[pdg_val[i]] @ W_q + b_q (gather fp32)
    gemm64<true, true, true, false, 4, 4><<<(S + 63) / 64, 256, 0, stream>>>(
        enc, pdg_val, pdg_key, Wt_q, b_q, qbuf, S, 256);

    // CSR segment softmax + pooling (gathers kv_all rows); overwrites qbuf
    pool_csr_kernel<<<(S + 3) / 4, 256, 0, stream>>>(
        qbuf, kv_all, offsets, sorted_src, S);

    // output projection to d_out (fp32), streaming bf16 A
    gemm64<false, false, false, true, 4, 4><<<(S + 63) / 64, 256, 0, stream>>>(
        qbuf, nullptr, nullptr, Wt_o, b_o, d_out, S, 256);
}

// Round 9
// 663.330 us; speedup vs baseline: 1.2696x; 1.0658x over previous
//
#include <hip/hip_runtime.h>
#include <hip/hip_bf16.h>

// ---------------------------------------------------------------------------
// CFGSubASTExpressionCombiner.
// Structure (r9): K|V projected for ALL N_AST rows by a B-STATIONARY streaming
// GEMM: each block stages a 256-col half of [Wk|Wv] in LDS ONCE (132 KB),
// then software-pipelines 32-row A tiles (fp32->bf16) through LDS; MFMA reads
// LDS only. Pool gathers kv_all[ast]. Q proj gathers; out proj streams.
// D = 256, H = 8, HD = 32, OUT = 256.
// NOTES:
//  - no hipMemsetAsync in the graph (in-graph small fills ~235us each, r3).
//  - scan is 3-phase multi-block (single-block scan was 233us on 1 CU, r4).
//  - r6 LDS 4-barrier/ktile fused GEMM: latency-bound (occ 22%, HBM 7%).
//  - r7 no-LDS direct-fragment GEMM: worse (B+A gather latency in MFMA pipe).
//  - r8 streaming A + B-from-L2-per-fragment: 17% HBM, 74us/block latency ->
//    B must be LDS-stationary and A-tile loads must overlap compute (this r).
// ---------------------------------------------------------------------------

typedef __attribute__((ext_vector_type(8))) short bf16x8;
typedef __attribute__((ext_vector_type(4))) float f32x4;

#define DEV __device__ __forceinline__

DEV float bf2f(unsigned short u) {
    union { unsigned int i; float f; } x;
    x.i = ((unsigned int)u) << 16;
    return x.f;
}

DEV unsigned short f2bf(float f) {
    union { float f; unsigned int i; } x;
    x.f = f;
    unsigned int i = x.i;
    unsigned int r = 0x7fffu + ((i >> 16) & 1u);   // round-to-nearest-even
    return (unsigned short)((i + r) >> 16);
}

// 8 consecutive fp32 -> bf16x8 via v_cvt_pk_bf16_f32 (4 instrs)
DEV bf16x8 cvt8(float4 lo, float4 hi) {
    union { bf16x8 v; unsigned int u[4]; } r;
    asm("v_cvt_pk_bf16_f32 %0, %1, %2" : "=v"(r.u[0]) : "v"(lo.x), "v"(lo.y));
    asm("v_cvt_pk_bf16_f32 %0, %1, %2" : "=v"(r.u[1]) : "v"(lo.z), "v"(lo.w));
    asm("v_cvt_pk_bf16_f32 %0, %1, %2" : "=v"(r.u[2]) : "v"(hi.x), "v"(hi.y));
    asm("v_cvt_pk_bf16_f32 %0, %1, %2" : "=v"(r.u[3]) : "v"(hi.z), "v"(hi.w));
    return r.v;
}

// ---------------------------------------------------------------------------
// Weight prep: Wt_q[256][256], Wt_kv[512][256] (K cols then V cols),
// Wt_o[256][256] in bf16 [N][K] layout; b_kv = bK|bV.
// ---------------------------------------------------------------------------
__global__ void convert_weights(const float* __restrict__ Wq,
                                const float* __restrict__ Wk,
                                const float* __restrict__ Wv,
                                const float* __restrict__ Wo,
                                const float* __restrict__ bk,
                                const float* __restrict__ bv,
                                unsigned short* __restrict__ Wtq,
                                unsigned short* __restrict__ Wtkv,
                                unsigned short* __restrict__ Wto,
                                float* __restrict__ bkv) {
    int t = blockIdx.x * 256 + threadIdx.x;
    if (t < 65536) {
        int n = t >> 8, k = t & 255;
        Wtq[t] = f2bf(Wq[k * 256 + n]);
    } else if (t < 65536 + 131072) {
        int u = t - 65536;
        int n = u >> 8, k = u & 255;
        Wtkv[u] = f2bf(n < 256 ? Wk[k * 256 + n] : Wv[k * 256 + (n - 256)]);
    } else if (t < 196608 + 65536) {
        int u = t - 196608;
        int n = u >> 8, k = u & 255;
        Wto[u] = f2bf(Wo[k * 256 + n]);
    } else if (t < 262144 + 512) {
        int c = t - 262144;
        bkv[c] = c < 256 ? bk[c] : bv[c - 256];
    }
}

// ---------------------------------------------------------------------------
// Counting sort of mapping entries by segment id.
// ---------------------------------------------------------------------------
__global__ void zero_kernel(int* __restrict__ p, int n) {
    int i = blockIdx.x * 256 + threadIdx.x;
    if (i < n) p[i] = 0;
}

__global__ void hist_kernel(const int* __restrict__ map_val,
                            int* __restrict__ counts, int M) {
    int m = blockIdx.x * 256 + threadIdx.x;
    if (m < M) atomicAdd(&counts[map_val[m]], 1);
}

// ---- 3-phase exclusive scan over counts[S] -> offsets[S+1], cursor[S] ----
__global__ __launch_bounds__(256) void scan_p1(const int* __restrict__ counts,
                                               int* __restrict__ bsum, int S) {
    const int i = blockIdx.x * 256 + threadIdx.x;
    int v = (i < S) ? counts[i] : 0;
#pragma unroll
    for (int d = 1; d < 64; d <<= 1) v += __shfl_xor(v, d);
    __shared__ int ws[4];
    if ((threadIdx.x & 63) == 0) ws[threadIdx.x >> 6] = v;
    __syncthreads();
    if (threadIdx.x == 0) bsum[blockIdx.x] = ws[0] + ws[1] + ws[2] + ws[3];
}

__global__ __launch_bounds__(256) void scan_p2(const int* __restrict__ bsum,
                                               int* __restrict__ bpref,
                                               int* __restrict__ offsets,
                                               int nb, int S) {
    __shared__ int part[256];
    const int t = threadIdx.x;
    const int chunk = (nb + 255) / 256;
    const int lo = t * chunk;
    const int hi = min(lo + chunk, nb);
    int sum = 0;
    for (int i = lo; i < hi; ++i) sum += bsum[i];
    part[t] = sum;
    __syncthreads();
    for (int d = 1; d < 256; d <<= 1) {
        int v = (t >= d) ? part[t - d] : 0;
        __syncthreads();
        part[t] += v;
        __syncthreads();
    }
    int run = (t > 0) ? part[t - 1] : 0;
    for (int i = lo; i < hi; ++i) {
        bpref[i] = run;
        run += bsum[i];
    }
    if (t == 255) offsets[S] = part[255];
}

__global__ __launch_bounds__(256) void scan_p3(const int* __restrict__ counts,
                                               const int* __restrict__ bpref,
                                               int* __restrict__ offsets,
                                               int* __restrict__ cursor, int S) {
    __shared__ int sh[256];
    const int t = threadIdx.x;
    const int i = blockIdx.x * 256 + t;
    const int v = (i < S) ? counts[i] : 0;
    sh[t] = v;
    __syncthreads();
    for (int d = 1; d < 256; d <<= 1) {
        int u = (t >= d) ? sh[t - d] : 0;
        __syncthreads();
        sh[t] += u;
        __syncthreads();
    }
    if (i < S) {
        const int e = sh[t] - v + bpref[blockIdx.x];
        offsets[i] = e;
        cursor[i] = e;
    }
}

__global__ void scatter_kernel(const int* __restrict__ map_key,
                               const int* __restrict__ map_val,
                               int* __restrict__ cursor,
                               int* __restrict__ sorted_src, int M) {
    int m = blockIdx.x * 256 + threadIdx.x;
    if (m >= M) return;
    int seg = map_val[m];
    int pos = atomicAdd(&cursor[seg], 1);
    sorted_src[pos] = map_key[m];   // ast row of this sorted entry
}

// ---------------------------------------------------------------------------
// B-stationary streaming K|V GEMM.
// Block = 512 thr (8 waves). blockIdx.y = column half (256 cols of [Wk|Wv]).
// Stage B-half in LDS once (256 x 258-padded bf16, ~132 KB). Grid-stride over
// 32-row A tiles: write A(t) to LDS -> barrier -> issue A(t+1) fp32 loads
// (in flight during compute) -> 8 k-steps x 4 MFMA from LDS -> stores ->
// barrier. Wave w owns cols w*32..+31. acc[2][2].
// ---------------------------------------------------------------------------
#define BP 258   // LDS row pitch (bf16 elems): +1 dword pad

__global__ __launch_bounds__(512, 1) void gemm_kv_stream(
    const float* __restrict__ enc,           // [N][256] fp32
    const unsigned short* __restrict__ Wtkv, // [512][256] bf16
    const float* __restrict__ bkv,           // [512]
    unsigned short* __restrict__ out,        // [N][512] bf16
    int nrows) {
    __shared__ unsigned short Bs[256 * BP];
    __shared__ unsigned short As[32 * BP];

    const int tid = threadIdx.x;
    const int colOff = blockIdx.y * 256;

    // ---- stage B half (one-time): rows colOff..+255 of Wtkv ----
    {
        const int r = tid >> 1;              // 0..255
        const int c0 = (tid & 1) * 128;
        const unsigned short* src = Wtkv + (long)(colOff + r) * 256 + c0;
#pragma unroll
        for (int u = 0; u < 128; u += 8)
            *(bf16x8*)(&Bs[r * BP + c0 + u]) = *(const bf16x8*)(src + u);
    }

    const int wave = tid >> 6, lane = tid & 63;
    const int lrow = lane & 15;
    const int koct = (lane >> 4) * 8;
    const int colb = wave * 32;

    const float bias0 = bkv[colOff + colb + lrow];
    const float bias1 = bkv[colOff + colb + 16 + lrow];

    // A staging coords: 32 rows x 256 elems = 8192 / 512 thr = 16 elems each
    const int srow = tid >> 4;               // 0..31
    const int scol = (tid & 15) * 16;

    const int ntiles = (nrows + 31) / 32;
    long t = blockIdx.x;

    // prologue: load tile t
    float4 f0, f1, f2, f3;
    {
        const long gr = t * 32 + srow;
        const float* ap = enc + (gr < nrows ? gr : 0) * 256 + scol;
        f0 = *(const float4*)(ap);
        f1 = *(const float4*)(ap + 4);
        f2 = *(const float4*)(ap + 8);
        f3 = *(const float4*)(ap + 12);
    }

    while (t < ntiles) {
        const long rbase = t * 32;

        // write A(t) into LDS
        *(bf16x8*)(&As[srow * BP + scol])     = cvt8(f0, f1);
        *(bf16x8*)(&As[srow * BP + scol + 8]) = cvt8(f2, f3);
        __syncthreads();

        // issue A(t+stride) loads -> in flight during compute
        const long tn = t + gridDim.x;
        {
            long gr = tn * 32 + srow;
            if (gr >= nrows) gr = 0;         // harmless read
            const float* ap = enc + gr * 256 + scol;
            f0 = *(const float4*)(ap);
            f1 = *(const float4*)(ap + 4);
            f2 = *(const float4*)(ap + 8);
            f3 = *(const float4*)(ap + 12);
        }

        // compute from LDS only
        f32x4 acc[2][2] = {};
#pragma unroll
        for (int kt = 0; kt < 8; ++kt) {
            const int k0 = kt * 32 + koct;
            bf16x8 a0 = *(const bf16x8*)(&As[lrow * BP + k0]);
            bf16x8 a1 = *(const bf16x8*)(&As[(16 + lrow) * BP + k0]);
            bf16x8 b0 = *(const bf16x8*)(&Bs[(colb + lrow) * BP + k0]);
            bf16x8 b1 = *(const bf16x8*)(&Bs[(colb + 16 + lrow) * BP + k0]);
            acc[0][0] = __builtin_amdgcn_mfma_f32_16x16x32_bf16(a0, b0, acc[0][0], 0, 0, 0);
            acc[0][1] = __builtin_amdgcn_mfma_f32_16x16x32_bf16(a0, b1, acc[0][1], 0, 0, 0);
            acc[1][0] = __builtin_amdgcn_mfma_f32_16x16x32_bf16(a1, b0, acc[1][0], 0, 0, 0);
            acc[1][1] = __builtin_amdgcn_mfma_f32_16x16x32_bf16(a1, b1, acc[1][1], 0, 0, 0);
        }

        // store C tile (col = lane&15, row = (lane>>4)*4+rj)
#pragma unroll
        for (int i = 0; i < 2; ++i)
#pragma unroll
            for (int j = 0; j < 2; ++j) {
                const int col = colOff + colb + j * 16 + lrow;
                const float bs = j ? bias1 : bias0;
#pragma unroll
                for (int rj = 0; rj < 4; ++rj) {
                    const long row = rbase + i * 16 + (lane >> 4) * 4 + rj;
                    if (row < nrows)
                        out[row * 512 + col] = f2bf(acc[i][j][rj] + bs);
                }
            }

        __syncthreads();   // all waves done reading As before next overwrite
        t = tn;
    }
}

// ---------------------------------------------------------------------------
// 64-row single-barrier GEMM (gather/scatter variants for Q and out proj).
// ---------------------------------------------------------------------------
template <bool GATHER, bool SCATTER, bool A_F32, bool OUT_F32, int NW, int MINB>
__global__ __launch_bounds__(NW * 64, MINB) void gemm64(
    const void* __restrict__ Aptr,
    const int* __restrict__ srcIdx,
    const int* __restrict__ dstIdx,
    const unsigned short* __restrict__ Wt,   // bf16 [NW*64][256]
    const float* __restrict__ bias,          // [NW*64]
    void* __restrict__ Out,
    int nrows, int ldo) {
    __shared__ unsigned short Alds[64][264];

    constexpr int NT = NW * 64;
    constexpr int F = 16384 / NT;   // elems staged per thread

    const int tid = threadIdx.x;
    const long rbase = (long)blockIdx.x * 64;

    // ---- stage A tile (64 rows x 256) ----
    {
        const int l0 = tid * F;
        const int row = l0 >> 8;
        const int col0 = l0 & 255;
        long gr = rbase + row;
        if (gr > nrows - 1) gr = nrows - 1;         // safe row; stores masked
        const long src = GATHER ? (long)srcIdx[gr] : gr;
        if constexpr (A_F32) {
            const float* ap = (const float*)Aptr + src * 256 + col0;
#pragma unroll
            for (int u = 0; u < F; u += 8) {
                const float4 lo = *(const float4*)(ap + u);
                const float4 hi = *(const float4*)(ap + u + 4);
                *(bf16x8*)(&Alds[row][col0 + u]) = cvt8(lo, hi);
            }
        } else {
            const unsigned short* ap = (const unsigned short*)Aptr + src * 256 + col0;
#pragma unroll
            for (int u = 0; u < F; u += 8)
                *(bf16x8*)(&Alds[row][col0 + u]) = *(const bf16x8*)(ap + u);
        }
    }
    __syncthreads();

    // ---- compute ----
    const int wave = tid >> 6, lane = tid & 63;
    const int lrow = lane & 15;
    const int koct = (lane >> 4) * 8;
    const int colb = wave * 64;

    f32x4 acc[4][4] = {};

#pragma unroll
    for (int kt = 0; kt < 8; ++kt) {
        const int k0 = kt * 32 + koct;
        bf16x8 a[4], b[4];
#pragma unroll
        for (int i = 0; i < 4; ++i)
            a[i] = *(const bf16x8*)(&Alds[i * 16 + lrow][k0]);
#pragma unroll
        for (int j = 0; j < 4; ++j)
            b[j] = *(const bf16x8*)(Wt + (long)(colb + j * 16 + lrow) * 256 + k0);
#pragma unroll
        for (int i = 0; i < 4; ++i)
#pragma unroll
            for (int j = 0; j < 4; ++j)
                acc[i][j] = __builtin_amdgcn_mfma_f32_16x16x32_bf16(a[i], b[j], acc[i][j], 0, 0, 0);
    }

    // ---- epilogue ----
#pragma unroll
    for (int i = 0; i < 4; ++i) {
#pragma unroll
        for (int j = 0; j < 4; ++j) {
            const int col = colb + j * 16 + lrow;
            const float bs = bias[col];
#pragma unroll
            for (int rj = 0; rj < 4; ++rj) {
                const long row = rbase + i * 16 + (lane >> 4) * 4 + rj;
                if (row < nrows) {
                    const long drow = SCATTER ? (long)dstIdx[row] : row;
                    const float val = acc[i][j][rj] + bs;
                    if constexpr (OUT_F32)
                        ((float*)Out)[drow * ldo + col] = val;
                    else
                        ((unsigned short*)Out)[drow * ldo + col] = f2bf(val);
                }
            }
        }
    }
}

// ---------------------------------------------------------------------------
// CSR pooling: one wave per segment s; entries e in [offsets[s],offsets[s+1]),
// each entry's K/V row is kv_all[sorted_src[e]] (gathered).
// ---------------------------------------------------------------------------
__global__ __launch_bounds__(256) void pool_csr_kernel(
    unsigned short* __restrict__ q,          // bf16 [S][256] (in: q, out: pooled)
    const unsigned short* __restrict__ kv,   // bf16 [N_AST][512] (k | v)
    const int* __restrict__ offsets,         // [S+1]
    const int* __restrict__ sorted_src,      // [M] ast row per sorted entry
    int S) {
    const int s = blockIdx.x * 4 + (threadIdx.x >> 6);
    if (s >= S) return;
    const int lane = threadIdx.x & 63;
    const int beg = offsets[s];
    const int end = offsets[s + 1];

    const ushort4 qv = *(const ushort4*)(q + (long)s * 256 + lane * 4);
    const float q0 = bf2f(qv.x), q1 = bf2f(qv.y), q2 = bf2f(qv.z), q3 = bf2f(qv.w);

    float a0 = 0.f, a1 = 0.f, a2 = 0.f, a3 = 0.f, denom = 0.f;

    for (int e = beg; e < end; ++e) {
        const long mrow = sorted_src[e];
        const ushort4 kk = *(const ushort4*)(kv + mrow * 512 + lane * 4);
        const ushort4 vv = *(const ushort4*)(kv + mrow * 512 + 256 + lane * 4);
        float p = q0 * bf2f(kk.x) + q1 * bf2f(kk.y) + q2 * bf2f(kk.z) + q3 * bf2f(kk.w);
        p += __shfl_xor(p, 1);
        p += __shfl_xor(p, 2);
        p += __shfl_xor(p, 4);   // 8-lane head group holds the head dot
        const float ew = expf(p * 0.17677669529663687f);  // 1/sqrt(32)
        a0 += ew * bf2f(vv.x);
        a1 += ew * bf2f(vv.y);
        a2 += ew * bf2f(vv.z);
        a3 += ew * bf2f(vv.w);
        denom += ew;
    }

    const float w = 1.0f / fmaxf(denom, 1e-9f);
    ushort4 o;
    o.x = f2bf(a0 * w);
    o.y = f2bf(a1 * w);
    o.z = f2bf(a2 * w);
    o.w = f2bf(a3 * w);
    *(ushort4*)(q + (long)s * 256 + lane * 4) = o;
}

// ---------------------------------------------------------------------------
extern "C" void kernel_launch(void* const* d_in, const int* in_sizes, int n_in,
                              void* d_out, int out_size, void* d_ws, size_t ws_size,
                              hipStream_t stream) {
    const float* enc  = (const float*)d_in[0];
    const float* W_q  = (const float*)d_in[1];
    const float* b_q  = (const float*)d_in[2];
    const float* W_k  = (const float*)d_in[3];
    const float* b_k  = (const float*)d_in[4];
    const float* W_v  = (const float*)d_in[5];
    const float* b_v  = (const float*)d_in[6];
    const float* W_o  = (const float*)d_in[7];
    const float* b_o  = (const float*)d_in[8];
    const int* map_key = (const int*)d_in[9];    // [M] ast idx
    const int* map_val = (const int*)d_in[10];   // [M] cfg idx (segment id)
    const int* pdg_key = (const int*)d_in[11];   // [S] dst rows (bijection)
    const int* pdg_val = (const int*)d_in[12];   // [S] src ast rows

    const int M = in_sizes[9];
    const int S = in_sizes[11];
    const int NAST = in_sizes[0] / 256;
    const int NB = (S + 255) / 256;

    char* ws = (char*)d_ws;
    size_t off = 0;
    auto alloc = [&](size_t bytes) -> char* {
        char* p = ws + off;
        off += (bytes + 255) & ~(size_t)255;
        return p;
    };

    unsigned short* Wt_q  = (unsigned short*)alloc(256 * 256 * 2);
    unsigned short* Wt_kv = (unsigned short*)alloc(512 * 256 * 2);
    unsigned short* Wt_o  = (unsigned short*)alloc(256 * 256 * 2);
    float*          b_kv  = (float*)alloc(512 * 4);
    int*            counts  = (int*)alloc((size_t)S * 4);
    int*            cursor  = (int*)alloc((size_t)S * 4);
    int*            offsets = (int*)alloc((size_t)(S + 1) * 4);
    int*            bsum    = (int*)alloc((size_t)NB * 4);
    int*            bpref   = (int*)alloc((size_t)NB * 4);
    int*            sorted_src = (int*)alloc((size_t)M * 4);
    unsigned short* qbuf   = (unsigned short*)alloc((size_t)S * 256 * 2);   // q, then pooled
    unsigned short* kv_all = (unsigned short*)alloc((size_t)NAST * 512 * 2);

    // zero counts with a plain kernel (NOT hipMemsetAsync)
    zero_kernel<<<(S + 255) / 256, 256, 0, stream>>>(counts, S);

    convert_weights<<<(262656 + 255) / 256, 256, 0, stream>>>(
        W_q, W_k, W_v, W_o, b_k, b_v, Wt_q, Wt_kv, Wt_o, b_kv);

    // counting sort of mapping entries by segment (CSR entry -> ast row)
    hist_kernel<<<(M + 255) / 256, 256, 0, stream>>>(map_val, counts, M);
    scan_p1<<<NB, 256, 0, stream>>>(counts, bsum, S);
    scan_p2<<<1, 256, 0, stream>>>(bsum, bpref, offsets, NB, S);
    scan_p3<<<NB, 256, 0, stream>>>(counts, bpref, offsets, cursor, S);
    scatter_kernel<<<(M + 255) / 256, 256, 0, stream>>>(
        map_key, map_val, cursor, sorted_src, M);

    // K|V projection for ALL ast rows: B-stationary streaming GEMM
    dim3 gkv(512, 2);
    gemm_kv_stream<<<gkv, 512, 0, stream>>>(enc, Wt_kv, b_kv, kv_all, NAST);

    // Q projection: q[pdg_key[i]] = enc[pdg_val[i]] @ W_q + b_q (gather fp32)
    gemm64<true, true, true, false, 4, 4><<<(S + 63) / 64, 256, 0, stream>>>(
        enc, pdg_val, pdg_key, Wt_q, b_q, qbuf, S, 256);

    // CSR segment softmax + pooling (gathers kv_all rows); overwrites qbuf
    pool_csr_kernel<<<(S + 3) / 4, 256, 0, stream>>>(
        qbuf, kv_all, offsets, sorted_src, S);

    // output projection to d_out (fp32), streaming bf16 A
    gemm64<false, false, false, true, 4, 4><<<(S + 63) / 64, 256, 0, stream>>>(
        qbuf, nullptr, nullptr, Wt_o, b_o, d_out, S, 256);
}

// Round 10
// 606.882 us; speedup vs baseline: 1.3877x; 1.0930x over previous
//
#include <hip/hip_runtime.h>
#include <hip/hip_bf16.h>

// ---------------------------------------------------------------------------
// CFGSubASTExpressionCombiner.
// Structure (r10): K|V projected for ALL N_AST rows (M == N_AST) by a
// B-stationary streaming GEMM: block stages a 256-col half of [Wk|Wv] in LDS
// once (XOR-swizzled), then pipelines 32-row A tiles. Epilogues use
// SWAPPED-OPERAND MFMA so each lane holds 4 consecutive output cols -> 8B/16B
// vector stores (r9 was store-issue-bound: 8192 2B stores/tile).
// Pool gathers kv_all[ast]. Q proj gathers; out proj streams.
// D = 256, H = 8, HD = 32, OUT = 256.
// NOTES:
//  - no hipMemsetAsync in the graph (in-graph small fills ~235us each, r3).
//  - scan is 3-phase multi-block (single-block scan was 233us on 1 CU, r4).
//  - r9: +1-dword LDS pad => 4-way b128 conflicts (6.2e7 cycles). Fix: XOR
//    swizzle 16B chunks (chunk ^= row&7) on write AND read => 2-way (free).
// ---------------------------------------------------------------------------

typedef __attribute__((ext_vector_type(8))) short bf16x8;
typedef __attribute__((ext_vector_type(4))) float f32x4;

#define DEV __device__ __forceinline__

DEV float bf2f(unsigned short u) {
    union { unsigned int i; float f; } x;
    x.i = ((unsigned int)u) << 16;
    return x.f;
}

DEV unsigned short f2bf(float f) {
    union { float f; unsigned int i; } x;
    x.f = f;
    unsigned int i = x.i;
    unsigned int r = 0x7fffu + ((i >> 16) & 1u);   // round-to-nearest-even
    return (unsigned short)((i + r) >> 16);
}

// 8 consecutive fp32 -> bf16x8 via v_cvt_pk_bf16_f32 (4 instrs)
DEV bf16x8 cvt8(float4 lo, float4 hi) {
    union { bf16x8 v; unsigned int u[4]; } r;
    asm("v_cvt_pk_bf16_f32 %0, %1, %2" : "=v"(r.u[0]) : "v"(lo.x), "v"(lo.y));
    asm("v_cvt_pk_bf16_f32 %0, %1, %2" : "=v"(r.u[1]) : "v"(lo.z), "v"(lo.w));
    asm("v_cvt_pk_bf16_f32 %0, %1, %2" : "=v"(r.u[2]) : "v"(hi.x), "v"(hi.y));
    asm("v_cvt_pk_bf16_f32 %0, %1, %2" : "=v"(r.u[3]) : "v"(hi.z), "v"(hi.w));
    return r.v;
}

// pack two f32 (+biases) into 4-col bf16 pairs for 8B stores
DEV unsigned int pack2(float a, float b) {
    unsigned int r;
    asm("v_cvt_pk_bf16_f32 %0, %1, %2" : "=v"(r) : "v"(a), "v"(b));
    return r;
}

// XOR-swizzled LDS index (ushort units); c must be a multiple of 8 elems.
DEV int swz(int row, int c) {
    return row * 256 + ((((c) >> 3) ^ (row & 7)) << 3);
}

// ---------------------------------------------------------------------------
// Weight prep: Wt_q[256][256], Wt_kv[512][256] (K cols then V cols),
// Wt_o[256][256] in bf16 [N][K] layout; b_kv = bK|bV.
// ---------------------------------------------------------------------------
__global__ void convert_weights(const float* __restrict__ Wq,
                                const float* __restrict__ Wk,
                                const float* __restrict__ Wv,
                                const float* __restrict__ Wo,
                                const float* __restrict__ bk,
                                const float* __restrict__ bv,
                                unsigned short* __restrict__ Wtq,
                                unsigned short* __restrict__ Wtkv,
                                unsigned short* __restrict__ Wto,
                                float* __restrict__ bkv) {
    int t = blockIdx.x * 256 + threadIdx.x;
    if (t < 65536) {
        int n = t >> 8, k = t & 255;
        Wtq[t] = f2bf(Wq[k * 256 + n]);
    } else if (t < 65536 + 131072) {
        int u = t - 65536;
        int n = u >> 8, k = u & 255;
        Wtkv[u] = f2bf(n < 256 ? Wk[k * 256 + n] : Wv[k * 256 + (n - 256)]);
    } else if (t < 196608 + 65536) {
        int u = t - 196608;
        int n = u >> 8, k = u & 255;
        Wto[u] = f2bf(Wo[k * 256 + n]);
    } else if (t < 262144 + 512) {
        int c = t - 262144;
        bkv[c] = c < 256 ? bk[c] : bv[c - 256];
    }
}

// ---------------------------------------------------------------------------
// Counting sort of mapping entries by segment id.
// ---------------------------------------------------------------------------
__global__ void zero_kernel(int* __restrict__ p, int n) {
    int i = blockIdx.x * 256 + threadIdx.x;
    if (i < n) p[i] = 0;
}

__global__ void hist_kernel(const int* __restrict__ map_val,
                            int* __restrict__ counts, int M) {
    int m = blockIdx.x * 256 + threadIdx.x;
    if (m < M) atomicAdd(&counts[map_val[m]], 1);
}

// ---- 3-phase exclusive scan over counts[S] -> offsets[S+1], cursor[S] ----
__global__ __launch_bounds__(256) void scan_p1(const int* __restrict__ counts,
                                               int* __restrict__ bsum, int S) {
    const int i = blockIdx.x * 256 + threadIdx.x;
    int v = (i < S) ? counts[i] : 0;
#pragma unroll
    for (int d = 1; d < 64; d <<= 1) v += __shfl_xor(v, d);
    __shared__ int ws[4];
    if ((threadIdx.x & 63) == 0) ws[threadIdx.x >> 6] = v;
    __syncthreads();
    if (threadIdx.x == 0) bsum[blockIdx.x] = ws[0] + ws[1] + ws[2] + ws[3];
}

__global__ __launch_bounds__(256) void scan_p2(const int* __restrict__ bsum,
                                               int* __restrict__ bpref,
                                               int* __restrict__ offsets,
                                               int nb, int S) {
    __shared__ int part[256];
    const int t = threadIdx.x;
    const int chunk = (nb + 255) / 256;
    const int lo = t * chunk;
    const int hi = min(lo + chunk, nb);
    int sum = 0;
    for (int i = lo; i < hi; ++i) sum += bsum[i];
    part[t] = sum;
    __syncthreads();
    for (int d = 1; d < 256; d <<= 1) {
        int v = (t >= d) ? part[t - d] : 0;
        __syncthreads();
        part[t] += v;
        __syncthreads();
    }
    int run = (t > 0) ? part[t - 1] : 0;
    for (int i = lo; i < hi; ++i) {
        bpref[i] = run;
        run += bsum[i];
    }
    if (t == 255) offsets[S] = part[255];
}

__global__ __launch_bounds__(256) void scan_p3(const int* __restrict__ counts,
                                               const int* __restrict__ bpref,
                                               int* __restrict__ offsets,
                                               int* __restrict__ cursor, int S) {
    __shared__ int sh[256];
    const int t = threadIdx.x;
    const int i = blockIdx.x * 256 + t;
    const int v = (i < S) ? counts[i] : 0;
    sh[t] = v;
    __syncthreads();
    for (int d = 1; d < 256; d <<= 1) {
        int u = (t >= d) ? sh[t - d] : 0;
        __syncthreads();
        sh[t] += u;
        __syncthreads();
    }
    if (i < S) {
        const int e = sh[t] - v + bpref[blockIdx.x];
        offsets[i] = e;
        cursor[i] = e;
    }
}

__global__ void scatter_kernel(const int* __restrict__ map_key,
                               const int* __restrict__ map_val,
                               int* __restrict__ cursor,
                               int* __restrict__ sorted_src, int M) {
    int m = blockIdx.x * 256 + threadIdx.x;
    if (m >= M) return;
    int seg = map_val[m];
    int pos = atomicAdd(&cursor[seg], 1);
    sorted_src[pos] = map_key[m];   // ast row of this sorted entry
}

// ---------------------------------------------------------------------------
// B-stationary streaming K|V GEMM (XOR-swizzled LDS, swapped-operand stores).
// Block = 512 thr (8 waves). blockIdx.y = 256-col half of [Wk|Wv]; B half
// staged once (131 KB). Grid-stride over 32-row A tiles with register
// prefetch of the next tile. Wave w owns cols w*32..+31. acc[2][2].
// Swapped mfma(b,a): lane holds output row (lane&15 + i*16) x 4 consecutive
// cols ((lane>>4)*4 + j*16) -> 8B stores.
// ---------------------------------------------------------------------------
__global__ __launch_bounds__(512, 1) void gemm_kv_stream(
    const float* __restrict__ enc,           // [N][256] fp32
    const unsigned short* __restrict__ Wtkv, // [512][256] bf16
    const float* __restrict__ bkv,           // [512]
    unsigned short* __restrict__ out,        // [N][512] bf16
    int nrows) {
    __shared__ unsigned short Bs[256 * 256];
    __shared__ unsigned short As[32 * 256];

    const int tid = threadIdx.x;
    const int colOff = blockIdx.y * 256;

    // ---- stage B half once (swizzled) ----
    {
        const int r = tid >> 1;              // 0..255
        const int c0 = (tid & 1) * 128;
        const unsigned short* src = Wtkv + (long)(colOff + r) * 256 + c0;
#pragma unroll
        for (int u = 0; u < 128; u += 8)
            *(bf16x8*)(&Bs[swz(r, c0 + u)]) = *(const bf16x8*)(src + u);
    }

    const int wave = tid >> 6, lane = tid & 63;
    const int lrow = lane & 15;
    const int koct = (lane >> 4) * 8;
    const int colb = wave * 32;

    // biases for this lane's 2x4 output cols
    const float4 bs0 = *(const float4*)(bkv + colOff + colb + (lane >> 4) * 4);
    const float4 bs1 = *(const float4*)(bkv + colOff + colb + 16 + (lane >> 4) * 4);

    // A staging coords: thread writes chunks c and c+128 of row srow
    const int srow = tid >> 4;               // 0..31
    const int cbase = (tid & 15) * 8;        // 0..120

    const int ntiles = (nrows + 31) / 32;
    long t = blockIdx.x;

    // prologue: load tile t
    float4 f0, f1, f2, f3;
    {
        const long gr = t * 32 + srow;
        const float* ap = enc + (gr < nrows ? gr : 0) * 256 + cbase;
        f0 = *(const float4*)(ap);
        f1 = *(const float4*)(ap + 4);
        f2 = *(const float4*)(ap + 128);
        f3 = *(const float4*)(ap + 132);
    }

    while (t < ntiles) {
        const long rbase = t * 32;

        // write A(t) into LDS (swizzled; chunks cbase and cbase+128 -> 2-way max)
        *(bf16x8*)(&As[swz(srow, cbase)])       = cvt8(f0, f1);
        *(bf16x8*)(&As[swz(srow, cbase + 128)]) = cvt8(f2, f3);
        __syncthreads();

        // issue A(t+stride) loads -> in flight during compute
        const long tn = t + gridDim.x;
        {
            long gr = tn * 32 + srow;
            if (gr >= nrows) gr = 0;         // harmless read
            const float* ap = enc + gr * 256 + cbase;
            f0 = *(const float4*)(ap);
            f1 = *(const float4*)(ap + 4);
            f2 = *(const float4*)(ap + 128);
            f3 = *(const float4*)(ap + 132);
        }

        // compute from LDS only (swapped operands)
        f32x4 acc[2][2] = {};
#pragma unroll
        for (int kt = 0; kt < 8; ++kt) {
            const int k0 = kt * 32 + koct;
            bf16x8 a0 = *(const bf16x8*)(&As[swz(lrow, k0)]);
            bf16x8 a1 = *(const bf16x8*)(&As[swz(16 + lrow, k0)]);
            bf16x8 b0 = *(const bf16x8*)(&Bs[swz(colb + lrow, k0)]);
            bf16x8 b1 = *(const bf16x8*)(&Bs[swz(colb + 16 + lrow, k0)]);
            acc[0][0] = __builtin_amdgcn_mfma_f32_16x16x32_bf16(b0, a0, acc[0][0], 0, 0, 0);
            acc[0][1] = __builtin_amdgcn_mfma_f32_16x16x32_bf16(b1, a0, acc[0][1], 0, 0, 0);
            acc[1][0] = __builtin_amdgcn_mfma_f32_16x16x32_bf16(b0, a1, acc[1][0], 0, 0, 0);
            acc[1][1] = __builtin_amdgcn_mfma_f32_16x16x32_bf16(b1, a1, acc[1][1], 0, 0, 0);
        }

        // stores: lane owns row rbase+i*16+lrow, cols colb+j*16+(lane>>4)*4..+3
#pragma unroll
        for (int i = 0; i < 2; ++i) {
            const long row = rbase + i * 16 + lrow;
            if (row < nrows) {
                unsigned short* orow = out + row * 512 + colOff + colb + (lane >> 4) * 4;
                uint2 w0, w1;
                w0.x = pack2(acc[i][0][0] + bs0.x, acc[i][0][1] + bs0.y);
                w0.y = pack2(acc[i][0][2] + bs0.z, acc[i][0][3] + bs0.w);
                w1.x = pack2(acc[i][1][0] + bs1.x, acc[i][1][1] + bs1.y);
                w1.y = pack2(acc[i][1][2] + bs1.z, acc[i][1][3] + bs1.w);
                *(uint2*)(orow)      = w0;
                *(uint2*)(orow + 16) = w1;
            }
        }

        __syncthreads();   // all waves done reading As before next overwrite
        t = tn;
    }
}

// ---------------------------------------------------------------------------
// 64-row single-barrier GEMM (gather/scatter variants for Q and out proj),
// swapped-operand epilogue (8B bf16 / 16B fp32 stores).
// ---------------------------------------------------------------------------
template <bool GATHER, bool SCATTER, bool A_F32, bool OUT_F32, int NW, int MINB>
__global__ __launch_bounds__(NW * 64, MINB) void gemm64(
    const void* __restrict__ Aptr,
    const int* __restrict__ srcIdx,
    const int* __restrict__ dstIdx,
    const unsigned short* __restrict__ Wt,   // bf16 [NW*64][256]
    const float* __restrict__ bias,          // [NW*64]
    void* __restrict__ Out,
    int nrows, int ldo) {
    __shared__ unsigned short Alds[64 * 256];

    constexpr int NT = NW * 64;
    constexpr int F = 16384 / NT;   // elems staged per thread

    const int tid = threadIdx.x;
    const long rbase = (long)blockIdx.x * 64;

    // ---- stage A tile (64 rows x 256), swizzled ----
    {
        const int l0 = tid * F;
        const int row = l0 >> 8;
        const int col0 = l0 & 255;
        long gr = rbase + row;
        if (gr > nrows - 1) gr = nrows - 1;         // safe row; stores masked
        const long src = GATHER ? (long)srcIdx[gr] : gr;
        if constexpr (A_F32) {
            const float* ap = (const float*)Aptr + src * 256 + col0;
#pragma unroll
            for (int u = 0; u < F; u += 8) {
                const float4 lo = *(const float4*)(ap + u);
                const float4 hi = *(const float4*)(ap + u + 4);
                *(bf16x8*)(&Alds[swz(row, col0 + u)]) = cvt8(lo, hi);
            }
        } else {
            const unsigned short* ap = (const unsigned short*)Aptr + src * 256 + col0;
#pragma unroll
            for (int u = 0; u < F; u += 8)
                *(bf16x8*)(&Alds[swz(row, col0 + u)]) = *(const bf16x8*)(ap + u);
        }
    }
    __syncthreads();

    // ---- compute (swapped operands) ----
    const int wave = tid >> 6, lane = tid & 63;
    const int lrow = lane & 15;
    const int koct = (lane >> 4) * 8;
    const int colb = wave * 64;

    f32x4 acc[4][4] = {};

#pragma unroll
    for (int kt = 0; kt < 8; ++kt) {
        const int k0 = kt * 32 + koct;
        bf16x8 a[4], b[4];
#pragma unroll
        for (int i = 0; i < 4; ++i)
            a[i] = *(const bf16x8*)(&Alds[swz(i * 16 + lrow, k0)]);
#pragma unroll
        for (int j = 0; j < 4; ++j)
            b[j] = *(const bf16x8*)(Wt + (long)(colb + j * 16 + lrow) * 256 + k0);
#pragma unroll
        for (int i = 0; i < 4; ++i)
#pragma unroll
            for (int j = 0; j < 4; ++j)
                acc[i][j] = __builtin_amdgcn_mfma_f32_16x16x32_bf16(b[j], a[i], acc[i][j], 0, 0, 0);
    }

    // ---- epilogue: lane holds row i*16+lrow, cols colb+j*16+(lane>>4)*4..+3
#pragma unroll
    for (int i = 0; i < 4; ++i) {
        const long row = rbase + i * 16 + lrow;
        if (row < nrows) {
            const long drow = SCATTER ? (long)dstIdx[row] : row;
#pragma unroll
            for (int j = 0; j < 4; ++j) {
                const int cb = colb + j * 16 + (lane >> 4) * 4;
                const float4 bs = *(const float4*)(bias + cb);
                if constexpr (OUT_F32) {
                    float4 v;
                    v.x = acc[i][j][0] + bs.x;
                    v.y = acc[i][j][1] + bs.y;
                    v.z = acc[i][j][2] + bs.z;
                    v.w = acc[i][j][3] + bs.w;
                    *(float4*)((float*)Out + drow * ldo + cb) = v;
                } else {
                    uint2 w;
                    w.x = pack2(acc[i][j][0] + bs.x, acc[i][j][1] + bs.y);
                    w.y = pack2(acc[i][j][2] + bs.z, acc[i][j][3] + bs.w);
                    *(uint2*)((unsigned short*)Out + drow * ldo + cb) = w;
                }
            }
        }
    }
}

// ---------------------------------------------------------------------------
// CSR pooling: one wave per segment s; entries e in [offsets[s],offsets[s+1]),
// each entry's K/V row is kv_all[sorted_src[e]] (gathered).
// ---------------------------------------------------------------------------
__global__ __launch_bounds__(256) void pool_csr_kernel(
    unsigned short* __restrict__ q,          // bf16 [S][256] (in: q, out: pooled)
    const unsigned short* __restrict__ kv,   // bf16 [N_AST][512] (k | v)
    const int* __restrict__ offsets,         // [S+1]
    const int* __restrict__ sorted_src,      // [M] ast row per sorted entry
    int S) {
    const int s = blockIdx.x * 4 + (threadIdx.x >> 6);
    if (s >= S) return;
    const int lane = threadIdx.x & 63;
    const int beg = offsets[s];
    const int end = offsets[s + 1];

    const ushort4 qv = *(const ushort4*)(q + (long)s * 256 + lane * 4);
    const float q0 = bf2f(qv.x), q1 = bf2f(qv.y), q2 = bf2f(qv.z), q3 = bf2f(qv.w);

    float a0 = 0.f, a1 = 0.f, a2 = 0.f, a3 = 0.f, denom = 0.f;

    for (int e = beg; e < end; ++e) {
        const long mrow = sorted_src[e];
        const ushort4 kk = *(const ushort4*)(kv + mrow * 512 + lane * 4);
        const ushort4 vv = *(const ushort4*)(kv + mrow * 512 + 256 + lane * 4);
        float p = q0 * bf2f(kk.x) + q1 * bf2f(kk.y) + q2 * bf2f(kk.z) + q3 * bf2f(kk.w);
        p += __shfl_xor(p, 1);
        p += __shfl_xor(p, 2);
        p += __shfl_xor(p, 4);   // 8-lane head group holds the head dot
        const float ew = expf(p * 0.17677669529663687f);  // 1/sqrt(32)
        a0 += ew * bf2f(vv.x);
        a1 += ew * bf2f(vv.y);
        a2 += ew * bf2f(vv.z);
        a3 += ew * bf2f(vv.w);
        denom += ew;
    }

    const float w = 1.0f / fmaxf(denom, 1e-9f);
    ushort4 o;
    o.x = f2bf(a0 * w);
    o.y = f2bf(a1 * w);
    o.z = f2bf(a2 * w);
    o.w = f2bf(a3 * w);
    *(ushort4*)(q + (long)s * 256 + lane * 4) = o;
}

// ---------------------------------------------------------------------------
extern "C" void kernel_launch(void* const* d_in, const int* in_sizes, int n_in,
                              void* d_out, int out_size, void* d_ws, size_t ws_size,
                              hipStream_t stream) {
    const float* enc  = (const float*)d_in[0];
    const float* W_q  = (const float*)d_in[1];
    const float* b_q  = (const float*)d_in[2];
    const float* W_k  = (const float*)d_in[3];
    const float* b_k  = (const float*)d_in[4];
    const float* W_v  = (const float*)d_in[5];
    const float* b_v  = (const float*)d_in[6];
    const float* W_o  = (const float*)d_in[7];
    const float* b_o  = (const float*)d_in[8];
    const int* map_key = (const int*)d_in[9];    // [M] ast idx
    const int* map_val = (const int*)d_in[10];   // [M] cfg idx (segment id)
    const int* pdg_key = (const int*)d_in[11];   // [S] dst rows (bijection)
    const int* pdg_val = (const int*)d_in[12];   // [S] src ast rows

    const int M = in_sizes[9];
    const int S = in_sizes[11];
    const int NAST = in_sizes[0] / 256;
    const int NB = (S + 255) / 256;

    char* ws = (char*)d_ws;
    size_t off = 0;
    auto alloc = [&](size_t bytes) -> char* {
        char* p = ws + off;
        off += (bytes + 255) & ~(size_t)255;
        return p;
    };

    unsigned short* Wt_q  = (unsigned short*)alloc(256 * 256 * 2);
    unsigned short* Wt_kv = (unsigned short*)alloc(512 * 256 * 2);
    unsigned short* Wt_o  = (unsigned short*)alloc(256 * 256 * 2);
    float*          b_kv  = (float*)alloc(512 * 4);
    int*            counts  = (int*)alloc((size_t)S * 4);
    int*            cursor  = (int*)alloc((size_t)S * 4);
    int*            offsets = (int*)alloc((size_t)(S + 1) * 4);
    int*            bsum    = (int*)alloc((size_t)NB * 4);
    int*            bpref   = (int*)alloc((size_t)NB * 4);
    int*            sorted_src = (int*)alloc((size_t)M * 4);
    unsigned short* qbuf   = (unsigned short*)alloc((size_t)S * 256 * 2);   // q, then pooled
    unsigned short* kv_all = (unsigned short*)alloc((size_t)NAST * 512 * 2);

    // zero counts with a plain kernel (NOT hipMemsetAsync)
    zero_kernel<<<(S + 255) / 256, 256, 0, stream>>>(counts, S);

    convert_weights<<<(262656 + 255) / 256, 256, 0, stream>>>(
        W_q, W_k, W_v, W_o, b_k, b_v, Wt_q, Wt_kv, Wt_o, b_kv);

    // counting sort of mapping entries by segment (CSR entry -> ast row)
    hist_kernel<<<(M + 255) / 256, 256, 0, stream>>>(map_val, counts, M);
    scan_p1<<<NB, 256, 0, stream>>>(counts, bsum, S);
    scan_p2<<<1, 256, 0, stream>>>(bsum, bpref, offsets, NB, S);
    scan_p3<<<NB, 256, 0, stream>>>(counts, bpref, offsets, cursor, S);
    scatter_kernel<<<(M + 255) / 256, 256, 0, stream>>>(
        map_key, map_val, cursor, sorted_src, M);

    // K|V projection for ALL ast rows: B-stationary streaming GEMM
    dim3 gkv(256, 2);
    gemm_kv_stream<<<gkv, 512, 0, stream>>>(enc, Wt_kv, b_kv, kv_all, NAST);

    // Q projection: q[pdg_key[i]] = enc[pdg_val[i]] @ W_q + b_q (gather fp32)
    gemm64<true, true, true, false, 4, 4><<<(S + 63) / 64, 256, 0, stream>>>(
        enc, pdg_val, pdg_key, Wt_q, b_q, qbuf, S, 256);

    // CSR segment softmax + pooling (gathers kv_all rows); overwrites qbuf
    pool_csr_kernel<<<(S + 3) / 4, 256, 0, stream>>>(
        qbuf, kv_all, offsets, sorted_src, S);

    // output projection to d_out (fp32), streaming bf16 A
    gemm64<false, false, false, true, 4, 4><<<(S + 63) / 64, 256, 0, stream>>>(
        qbuf, nullptr, nullptr, Wt_o, b_o, d_out, S, 256);
}

// Round 11
// 519.203 us; speedup vs baseline: 1.6221x; 1.1689x over previous
//
#include <hip/hip_runtime.h>
#include <hip/hip_bf16.h>

// ---------------------------------------------------------------------------
// CFGSubASTExpressionCombiner.
// Structure (r11): K|V for ALL N_AST rows via a B-REGISTER streaming GEMM:
// 1024-thr block (16 waves x 32 cols = all 512 cols, enc read ONCE). B lives
// in 64 VGPRs/lane (loaded once from L2); A = 32-row fp32 tiles double-
// buffered in 2x16KB LDS (XOR-swizzled), ONE barrier per tile. Swapped-operand
// MFMA epilogue -> 8B stores. Pool gathers kv_all[ast]; Q proj gathers;
// out proj streams. D = 256, H = 8, HD = 32, OUT = 256.
// NOTES:
//  - no hipMemsetAsync in the graph (in-graph small fills ~235us each, r3).
//  - scan is 3-phase multi-block (single-block scan was 233us on 1 CU, r4).
//  - r9/r10: B-in-LDS = half the LDS traffic + 147KB -> 1 block/CU; grid.y=2
//    read enc twice. This round: B in regs, LDS 33KB, single enc pass.
// ---------------------------------------------------------------------------

typedef __attribute__((ext_vector_type(8))) short bf16x8;
typedef __attribute__((ext_vector_type(4))) float f32x4;

#define DEV __device__ __forceinline__

DEV float bf2f(unsigned short u) {
    union { unsigned int i; float f; } x;
    x.i = ((unsigned int)u) << 16;
    return x.f;
}

DEV unsigned short f2bf(float f) {
    union { float f; unsigned int i; } x;
    x.f = f;
    unsigned int i = x.i;
    unsigned int r = 0x7fffu + ((i >> 16) & 1u);   // round-to-nearest-even
    return (unsigned short)((i + r) >> 16);
}

// 8 consecutive fp32 -> bf16x8 via v_cvt_pk_bf16_f32 (4 instrs)
DEV bf16x8 cvt8(float4 lo, float4 hi) {
    union { bf16x8 v; unsigned int u[4]; } r;
    asm("v_cvt_pk_bf16_f32 %0, %1, %2" : "=v"(r.u[0]) : "v"(lo.x), "v"(lo.y));
    asm("v_cvt_pk_bf16_f32 %0, %1, %2" : "=v"(r.u[1]) : "v"(lo.z), "v"(lo.w));
    asm("v_cvt_pk_bf16_f32 %0, %1, %2" : "=v"(r.u[2]) : "v"(hi.x), "v"(hi.y));
    asm("v_cvt_pk_bf16_f32 %0, %1, %2" : "=v"(r.u[3]) : "v"(hi.z), "v"(hi.w));
    return r.v;
}

// pack two f32 into 2 bf16 (one dword) for vector stores
DEV unsigned int pack2(float a, float b) {
    unsigned int r;
    asm("v_cvt_pk_bf16_f32 %0, %1, %2" : "=v"(r) : "v"(a), "v"(b));
    return r;
}

// XOR-swizzled LDS index (ushort units); c must be a multiple of 8 elems.
DEV int swz(int row, int c) {
    return row * 256 + ((((c) >> 3) ^ (row & 7)) << 3);
}

// ---------------------------------------------------------------------------
// Weight prep: Wt_q[256][256], Wt_kv[512][256] (K cols then V cols),
// Wt_o[256][256] in bf16 [N][K] layout; b_kv = bK|bV.
// ---------------------------------------------------------------------------
__global__ void convert_weights(const float* __restrict__ Wq,
                                const float* __restrict__ Wk,
                                const float* __restrict__ Wv,
                                const float* __restrict__ Wo,
                                const float* __restrict__ bk,
                                const float* __restrict__ bv,
                                unsigned short* __restrict__ Wtq,
                                unsigned short* __restrict__ Wtkv,
                                unsigned short* __restrict__ Wto,
                                float* __restrict__ bkv) {
    int t = blockIdx.x * 256 + threadIdx.x;
    if (t < 65536) {
        int n = t >> 8, k = t & 255;
        Wtq[t] = f2bf(Wq[k * 256 + n]);
    } else if (t < 65536 + 131072) {
        int u = t - 65536;
        int n = u >> 8, k = u & 255;
        Wtkv[u] = f2bf(n < 256 ? Wk[k * 256 + n] : Wv[k * 256 + (n - 256)]);
    } else if (t < 196608 + 65536) {
        int u = t - 196608;
        int n = u >> 8, k = u & 255;
        Wto[u] = f2bf(Wo[k * 256 + n]);
    } else if (t < 262144 + 512) {
        int c = t - 262144;
        bkv[c] = c < 256 ? bk[c] : bv[c - 256];
    }
}

// ---------------------------------------------------------------------------
// Counting sort of mapping entries by segment id.
// ---------------------------------------------------------------------------
__global__ void zero_kernel(int* __restrict__ p, int n) {
    int i = blockIdx.x * 256 + threadIdx.x;
    if (i < n) p[i] = 0;
}

__global__ void hist_kernel(const int* __restrict__ map_val,
                            int* __restrict__ counts, int M) {
    int m = blockIdx.x * 256 + threadIdx.x;
    if (m < M) atomicAdd(&counts[map_val[m]], 1);
}

// ---- 3-phase exclusive scan over counts[S] -> offsets[S+1], cursor[S] ----
__global__ __launch_bounds__(256) void scan_p1(const int* __restrict__ counts,
                                               int* __restrict__ bsum, int S) {
    const int i = blockIdx.x * 256 + threadIdx.x;
    int v = (i < S) ? counts[i] : 0;
#pragma unroll
    for (int d = 1; d < 64; d <<= 1) v += __shfl_xor(v, d);
    __shared__ int ws[4];
    if ((threadIdx.x & 63) == 0) ws[threadIdx.x >> 6] = v;
    __syncthreads();
    if (threadIdx.x == 0) bsum[blockIdx.x] = ws[0] + ws[1] + ws[2] + ws[3];
}

__global__ __launch_bounds__(256) void scan_p2(const int* __restrict__ bsum,
                                               int* __restrict__ bpref,
                                               int* __restrict__ offsets,
                                               int nb, int S) {
    __shared__ int part[256];
    const int t = threadIdx.x;
    const int chunk = (nb + 255) / 256;
    const int lo = t * chunk;
    const int hi = min(lo + chunk, nb);
    int sum = 0;
    for (int i = lo; i < hi; ++i) sum += bsum[i];
    part[t] = sum;
    __syncthreads();
    for (int d = 1; d < 256; d <<= 1) {
        int v = (t >= d) ? part[t - d] : 0;
        __syncthreads();
        part[t] += v;
        __syncthreads();
    }
    int run = (t > 0) ? part[t - 1] : 0;
    for (int i = lo; i < hi; ++i) {
        bpref[i] = run;
        run += bsum[i];
    }
    if (t == 255) offsets[S] = part[255];
}

__global__ __launch_bounds__(256) void scan_p3(const int* __restrict__ counts,
                                               const int* __restrict__ bpref,
                                               int* __restrict__ offsets,
                                               int* __restrict__ cursor, int S) {
    __shared__ int sh[256];
    const int t = threadIdx.x;
    const int i = blockIdx.x * 256 + t;
    const int v = (i < S) ? counts[i] : 0;
    sh[t] = v;
    __syncthreads();
    for (int d = 1; d < 256; d <<= 1) {
        int u = (t >= d) ? sh[t - d] : 0;
        __syncthreads();
        sh[t] += u;
        __syncthreads();
    }
    if (i < S) {
        const int e = sh[t] - v + bpref[blockIdx.x];
        offsets[i] = e;
        cursor[i] = e;
    }
}

__global__ void scatter_kernel(const int* __restrict__ map_key,
                               const int* __restrict__ map_val,
                               int* __restrict__ cursor,
                               int* __restrict__ sorted_src, int M) {
    int m = blockIdx.x * 256 + threadIdx.x;
    if (m >= M) return;
    int seg = map_val[m];
    int pos = atomicAdd(&cursor[seg], 1);
    sorted_src[pos] = map_key[m];   // ast row of this sorted entry
}

// ---------------------------------------------------------------------------
// B-register streaming K|V GEMM.
// Block = 1024 thr (16 waves). Wave w owns output cols w*32..+31 of 512.
// B fragments (16 x bf16x8 = 64 VGPR/lane) loaded once from L2-resident Wtkv.
// A: 32-row fp32 tiles, double-buffered in LDS (2 x 16KB, XOR-swizzled),
// ONE barrier per tile. Swapped-operand MFMA: lane stores rows {lrow,16+lrow}
// x 4 consecutive cols per 16-col block -> 8B stores.
// ---------------------------------------------------------------------------
__global__ __launch_bounds__(1024, 4) void gemm_kv_stream(
    const float* __restrict__ enc,           // [N][256] fp32
    const unsigned short* __restrict__ Wtkv, // [512][256] bf16
    const float* __restrict__ bkv,           // [512]
    unsigned short* __restrict__ out,        // [N][512] bf16
    int nrows) {
    __shared__ unsigned short As[2][32 * 256];

    const int tid = threadIdx.x;
    const int wave = tid >> 6, lane = tid & 63;
    const int lrow = lane & 15;
    const int koct = (lane >> 4) * 8;
    const int colb = wave * 32;

    // ---- B into registers (once, from L2) ----
    bf16x8 B0[8], B1[8];
#pragma unroll
    for (int kt = 0; kt < 8; ++kt) {
        B0[kt] = *(const bf16x8*)(Wtkv + (long)(colb + lrow) * 256 + kt * 32 + koct);
        B1[kt] = *(const bf16x8*)(Wtkv + (long)(colb + 16 + lrow) * 256 + kt * 32 + koct);
    }
    const float4 bs0 = *(const float4*)(bkv + colb + (lane >> 4) * 4);
    const float4 bs1 = *(const float4*)(bkv + colb + 16 + (lane >> 4) * 4);

    // A staging: 1024 thr x 8 fp32 = 32x256 tile
    const int srow = tid >> 5;        // 0..31
    const int scol = (tid & 31) * 8;  // 16B chunk

    const int ntiles = (nrows + 31) / 32;
    const int stride = gridDim.x;
    long t = blockIdx.x;

    // prologue: load tile t into regs
    float4 f0, f1;
    {
        const long gr = t * 32 + srow;
        const float* ap = enc + (gr < nrows ? gr : 0) * 256 + scol;
        f0 = *(const float4*)(ap);
        f1 = *(const float4*)(ap + 4);
    }

    int cur = 0;
    while (t < ntiles) {
        // write A(t) into current buffer (swizzled)
        *(bf16x8*)(&As[cur][swz(srow, scol)]) = cvt8(f0, f1);
        __syncthreads();

        // issue A(t+stride) loads -> complete during compute
        const long tn = t + stride;
        {
            long gr = tn * 32 + srow;
            if (gr >= nrows) gr = 0;    // harmless read
            const float* ap = enc + gr * 256 + scol;
            f0 = *(const float4*)(ap);
            f1 = *(const float4*)(ap + 4);
        }

        // compute: A from LDS, B from registers
        f32x4 acc[2][2] = {};
#pragma unroll
        for (int kt = 0; kt < 8; ++kt) {
            const int k0 = kt * 32 + koct;
            bf16x8 a0 = *(const bf16x8*)(&As[cur][swz(lrow, k0)]);
            bf16x8 a1 = *(const bf16x8*)(&As[cur][swz(16 + lrow, k0)]);
            acc[0][0] = __builtin_amdgcn_mfma_f32_16x16x32_bf16(B0[kt], a0, acc[0][0], 0, 0, 0);
            acc[0][1] = __builtin_amdgcn_mfma_f32_16x16x32_bf16(B1[kt], a0, acc[0][1], 0, 0, 0);
            acc[1][0] = __builtin_amdgcn_mfma_f32_16x16x32_bf16(B0[kt], a1, acc[1][0], 0, 0, 0);
            acc[1][1] = __builtin_amdgcn_mfma_f32_16x16x32_bf16(B1[kt], a1, acc[1][1], 0, 0, 0);
        }

        // stores: lane owns rows {t*32+i*16+lrow}, cols colb+j*16+(lane>>4)*4..+3
        const long rbase = t * 32;
#pragma unroll
        for (int i = 0; i < 2; ++i) {
            const long row = rbase + i * 16 + lrow;
            if (row < nrows) {
                unsigned short* orow = out + row * 512 + colb + (lane >> 4) * 4;
                uint2 w0, w1;
                w0.x = pack2(acc[i][0][0] + bs0.x, acc[i][0][1] + bs0.y);
                w0.y = pack2(acc[i][0][2] + bs0.z, acc[i][0][3] + bs0.w);
                w1.x = pack2(acc[i][1][0] + bs1.x, acc[i][1][1] + bs1.y);
                w1.y = pack2(acc[i][1][2] + bs1.z, acc[i][1][3] + bs1.w);
                *(uint2*)(orow)      = w0;
                *(uint2*)(orow + 16) = w1;
            }
        }

        cur ^= 1;
        t = tn;
    }
}

// ---------------------------------------------------------------------------
// 64-row single-barrier GEMM (gather/scatter variants for Q and out proj),
// swapped-operand epilogue (8B bf16 / 16B fp32 stores).
// ---------------------------------------------------------------------------
template <bool GATHER, bool SCATTER, bool A_F32, bool OUT_F32, int NW, int MINB>
__global__ __launch_bounds__(NW * 64, MINB) void gemm64(
    const void* __restrict__ Aptr,
    const int* __restrict__ srcIdx,
    const int* __restrict__ dstIdx,
    const unsigned short* __restrict__ Wt,   // bf16 [NW*64][256]
    const float* __restrict__ bias,          // [NW*64]
    void* __restrict__ Out,
    int nrows, int ldo) {
    __shared__ unsigned short Alds[64 * 256];

    constexpr int NT = NW * 64;
    constexpr int F = 16384 / NT;   // elems staged per thread

    const int tid = threadIdx.x;
    const long rbase = (long)blockIdx.x * 64;

    // ---- stage A tile (64 rows x 256), swizzled ----
    {
        const int l0 = tid * F;
        const int row = l0 >> 8;
        const int col0 = l0 & 255;
        long gr = rbase + row;
        if (gr > nrows - 1) gr = nrows - 1;         // safe row; stores masked
        const long src = GATHER ? (long)srcIdx[gr] : gr;
        if constexpr (A_F32) {
            const float* ap = (const float*)Aptr + src * 256 + col0;
#pragma unroll
            for (int u = 0; u < F; u += 8) {
                const float4 lo = *(const float4*)(ap + u);
                const float4 hi = *(const float4*)(ap + u + 4);
                *(bf16x8*)(&Alds[swz(row, col0 + u)]) = cvt8(lo, hi);
            }
        } else {
            const unsigned short* ap = (const unsigned short*)Aptr + src * 256 + col0;
#pragma unroll
            for (int u = 0; u < F; u += 8)
                *(bf16x8*)(&Alds[swz(row, col0 + u)]) = *(const bf16x8*)(ap + u);
        }
    }
    __syncthreads();

    // ---- compute (swapped operands) ----
    const int wave = tid >> 6, lane = tid & 63;
    const int lrow = lane & 15;
    const int koct = (lane >> 4) * 8;
    const int colb = wave * 64;

    f32x4 acc[4][4] = {};

#pragma unroll
    for (int kt = 0; kt < 8; ++kt) {
        const int k0 = kt * 32 + koct;
        bf16x8 a[4], b[4];
#pragma unroll
        for (int i = 0; i < 4; ++i)
            a[i] = *(const bf16x8*)(&Alds[swz(i * 16 + lrow, k0)]);
#pragma unroll
        for (int j = 0; j < 4; ++j)
            b[j] = *(const bf16x8*)(Wt + (long)(colb + j * 16 + lrow) * 256 + k0);
#pragma unroll
        for (int i = 0; i < 4; ++i)
#pragma unroll
            for (int j = 0; j < 4; ++j)
                acc[i][j] = __builtin_amdgcn_mfma_f32_16x16x32_bf16(b[j], a[i], acc[i][j], 0, 0, 0);
    }

    // ---- epilogue: lane holds row i*16+lrow, cols colb+j*16+(lane>>4)*4..+3
#pragma unroll
    for (int i = 0; i < 4; ++i) {
        const long row = rbase + i * 16 + lrow;
        if (row < nrows) {
            const long drow = SCATTER ? (long)dstIdx[row] : row;
#pragma unroll
            for (int j = 0; j < 4; ++j) {
                const int cb = colb + j * 16 + (lane >> 4) * 4;
                const float4 bs = *(const float4*)(bias + cb);
                if constexpr (OUT_F32) {
                    float4 v;
                    v.x = acc[i][j][0] + bs.x;
                    v.y = acc[i][j][1] + bs.y;
                    v.z = acc[i][j][2] + bs.z;
                    v.w = acc[i][j][3] + bs.w;
                    *(float4*)((float*)Out + drow * ldo + cb) = v;
                } else {
                    uint2 w;
                    w.x = pack2(acc[i][j][0] + bs.x, acc[i][j][1] + bs.y);
                    w.y = pack2(acc[i][j][2] + bs.z, acc[i][j][3] + bs.w);
                    *(uint2*)((unsigned short*)Out + drow * ldo + cb) = w;
                }
            }
        }
    }
}

// ---------------------------------------------------------------------------
// CSR pooling: one wave per segment s; entries e in [offsets[s],offsets[s+1]),
// each entry's K/V row is kv_all[sorted_src[e]] (gathered).
// ---------------------------------------------------------------------------
__global__ __launch_bounds__(256) void pool_csr_kernel(
    unsigned short* __restrict__ q,          // bf16 [S][256] (in: q, out: pooled)
    const unsigned short* __restrict__ kv,   // bf16 [N_AST][512] (k | v)
    const int* __restrict__ offsets,         // [S+1]
    const int* __restrict__ sorted_src,      // [M] ast row per sorted entry
    int S) {
    const int s = blockIdx.x * 4 + (threadIdx.x >> 6);
    if (s >= S) return;
    const int lane = threadIdx.x & 63;
    const int beg = offsets[s];
    const int end = offsets[s + 1];

    const ushort4 qv = *(const ushort4*)(q + (long)s * 256 + lane * 4);
    const float q0 = bf2f(qv.x), q1 = bf2f(qv.y), q2 = bf2f(qv.z), q3 = bf2f(qv.w);

    float a0 = 0.f, a1 = 0.f, a2 = 0.f, a3 = 0.f, denom = 0.f;

    for (int e = beg; e < end; ++e) {
        const long mrow = sorted_src[e];
        const ushort4 kk = *(const ushort4*)(kv + mrow * 512 + lane * 4);
        const ushort4 vv = *(const ushort4*)(kv + mrow * 512 + 256 + lane * 4);
        float p = q0 * bf2f(kk.x) + q1 * bf2f(kk.y) + q2 * bf2f(kk.z) + q3 * bf2f(kk.w);
        p += __shfl_xor(p, 1);
        p += __shfl_xor(p, 2);
        p += __shfl_xor(p, 4);   // 8-lane head group holds the head dot
        const float ew = expf(p * 0.17677669529663687f);  // 1/sqrt(32)
        a0 += ew * bf2f(vv.x);
        a1 += ew * bf2f(vv.y);
        a2 += ew * bf2f(vv.z);
        a3 += ew * bf2f(vv.w);
        denom += ew;
    }

    const float w = 1.0f / fmaxf(denom, 1e-9f);
    ushort4 o;
    o.x = f2bf(a0 * w);
    o.y = f2bf(a1 * w);
    o.z = f2bf(a2 * w);
    o.w = f2bf(a3 * w);
    *(ushort4*)(q + (long)s * 256 + lane * 4) = o;
}

// ---------------------------------------------------------------------------
extern "C" void kernel_launch(void* const* d_in, const int* in_sizes, int n_in,
                              void* d_out, int out_size, void* d_ws, size_t ws_size,
                              hipStream_t stream) {
    const float* enc  = (const float*)d_in[0];
    const float* W_q  = (const float*)d_in[1];
    const float* b_q  = (const float*)d_in[2];
    const float* W_k  = (const float*)d_in[3];
    const float* b_k  = (const float*)d_in[4];
    const float* W_v  = (const float*)d_in[5];
    const float* b_v  = (const float*)d_in[6];
    const float* W_o  = (const float*)d_in[7];
    const float* b_o  = (const float*)d_in[8];
    const int* map_key = (const int*)d_in[9];    // [M] ast idx
    const int* map_val = (const int*)d_in[10];   // [M] cfg idx (segment id)
    const int* pdg_key = (const int*)d_in[11];   // [S] dst rows (bijection)
    const int* pdg_val = (const int*)d_in[12];   // [S] src ast rows

    const int M = in_sizes[9];
    const int S = in_sizes[11];
    const int NAST = in_sizes[0] / 256;
    const int NB = (S + 255) / 256;

    char* ws = (char*)d_ws;
    size_t off = 0;
    auto alloc = [&](size_t bytes) -> char* {
        char* p = ws + off;
        off += (bytes + 255) & ~(size_t)255;
        return p;
    };

    unsigned short* Wt_q  = (unsigned short*)alloc(256 * 256 * 2);
    unsigned short* Wt_kv = (unsigned short*)alloc(512 * 256 * 2);
    unsigned short* Wt_o  = (unsigned short*)alloc(256 * 256 * 2);
    float*          b_kv  = (float*)alloc(512 * 4);
    int*            counts  = (int*)alloc((size_t)S * 4);
    int*            cursor  = (int*)alloc((size_t)S * 4);
    int*            offsets = (int*)alloc((size_t)(S + 1) * 4);
    int*            bsum    = (int*)alloc((size_t)NB * 4);
    int*            bpref   = (int*)alloc((size_t)NB * 4);
    int*            sorted_src = (int*)alloc((size_t)M * 4);
    unsigned short* qbuf   = (unsigned short*)alloc((size_t)S * 256 * 2);   // q, then pooled
    unsigned short* kv_all = (unsigned short*)alloc((size_t)NAST * 512 * 2);

    // zero counts with a plain kernel (NOT hipMemsetAsync)
    zero_kernel<<<(S + 255) / 256, 256, 0, stream>>>(counts, S);

    convert_weights<<<(262656 + 255) / 256, 256, 0, stream>>>(
        W_q, W_k, W_v, W_o, b_k, b_v, Wt_q, Wt_kv, Wt_o, b_kv);

    // counting sort of mapping entries by segment (CSR entry -> ast row)
    hist_kernel<<<(M + 255) / 256, 256, 0, stream>>>(map_val, counts, M);
    scan_p1<<<NB, 256, 0, stream>>>(counts, bsum, S);
    scan_p2<<<1, 256, 0, stream>>>(bsum, bpref, offsets, NB, S);
    scan_p3<<<NB, 256, 0, stream>>>(counts, bpref, offsets, cursor, S);
    scatter_kernel<<<(M + 255) / 256, 256, 0, stream>>>(
        map_key, map_val, cursor, sorted_src, M);

    // K|V projection for ALL ast rows: B-register streaming GEMM (enc once)
    gemm_kv_stream<<<256, 1024, 0, stream>>>(enc, Wt_kv, b_kv, kv_all, NAST);

    // Q projection: q[pdg_key[i]] = enc[pdg_val[i]] @ W_q + b_q (gather fp32)
    gemm64<true, true, true, false, 4, 4><<<(S + 63) / 64, 256, 0, stream>>>(
        enc, pdg_val, pdg_key, Wt_q, b_q, qbuf, S, 256);

    // CSR segment softmax + pooling (gathers kv_all rows); overwrites qbuf
    pool_csr_kernel<<<(S + 3) / 4, 256, 0, stream>>>(
        qbuf, kv_all, offsets, sorted_src, S);

    // output projection to d_out (fp32), streaming bf16 A
    gemm64<false, false, false, true, 4, 4><<<(S + 63) / 64, 256, 0, stream>>>(
        qbuf, nullptr, nullptr, Wt_o, b_o, d_out, S, 256);
}